// Round 2
// baseline (7328.884 us; speedup 1.0000x reference)
//
#include <hip/hip_runtime.h>

#define CDIV(a,b) (((a)+(b)-1)/(b))

typedef __attribute__((ext_vector_type(8))) short bf16x8;
typedef __attribute__((ext_vector_type(4))) float floatx4;

__device__ __forceinline__ ushort f2bf(float x) {
    unsigned u = __float_as_uint(x);
    return (ushort)((u + 0x7fffu + ((u >> 16) & 1u)) >> 16);   // RNE
}
__device__ __forceinline__ float bf2f(ushort h) {
    return __uint_as_float(((unsigned)h) << 16);
}

// ---------------- utility kernels ----------------

__global__ void zero_f4(float4* __restrict__ p, long long n4) {
    long long i = blockIdx.x * 256LL + threadIdx.x;
    if (i < n4) p[i] = make_float4(0.f, 0.f, 0.f, 0.f);
}

// convert fp32 -> bf16, 8 elems/thread
__global__ void cvt_bf16_k(const float4* __restrict__ in, uint4* __restrict__ out, long long n8) {
    long long i = blockIdx.x * 256LL + threadIdx.x;
    if (i >= n8) return;
    float4 a = in[2 * i], b = in[2 * i + 1];
    uint4 o;
    o.x = (unsigned)f2bf(a.x) | ((unsigned)f2bf(a.y) << 16);
    o.y = (unsigned)f2bf(a.z) | ((unsigned)f2bf(a.w) << 16);
    o.z = (unsigned)f2bf(b.x) | ((unsigned)f2bf(b.y) << 16);
    o.w = (unsigned)f2bf(b.z) | ((unsigned)f2bf(b.w) << 16);
    out[i] = o;
}

// Bt[(col0+n)*K + k] = c0*basis[k*N+n] + c1*basis[KN + k*N+n]   (bf16 out, transposed)
__global__ void fill_basis_T(ushort* __restrict__ out, int K, int col0,
                             const float* __restrict__ basis, long long KN,
                             const float* __restrict__ coeff, int r, int N, long long total) {
    long long i = blockIdx.x * 256LL + threadIdx.x;
    if (i >= total) return;
    int k = (int)(i % K), n = (int)(i / K);
    float c0 = coeff[2 * r], c1 = coeff[2 * r + 1];
    out[(size_t)(col0 + n) * K + k] = f2bf(c0 * basis[(size_t)k * N + n] + c1 * basis[KN + (size_t)k * N + n]);
}

__global__ void fill_copy_T(ushort* __restrict__ out, int K, int col0,
                            const float* __restrict__ src, int N, long long total) {
    long long i = blockIdx.x * 256LL + threadIdx.x;
    if (i >= total) return;
    int k = (int)(i % K), n = (int)(i / K);
    out[(size_t)(col0 + n) * K + k] = f2bf(src[(size_t)k * N + n]);
}

__global__ void accum_deg(const int* __restrict__ dst, int n, float* __restrict__ deg) {
    int i = blockIdx.x * 256 + threadIdx.x;
    if (i < n) atomicAdd(&deg[dst[i]], 1.0f);
}

__global__ void invert_deg(float* __restrict__ deg, int n) {
    int i = blockIdx.x * 256 + threadIdx.x;
    if (i < n) deg[i] = 1.0f / fmaxf(deg[i], 1.0f);
}

// ---------------- MFMA GEMM: C[M,N] bf16 = A[M,K] bf16 @ Bt[N,K]^T bf16 ----------------
// requires K%32==0, N%128==0; M arbitrary. 128x128 tile, 256 threads (4 waves, 2x2 of 64x64).
__global__ __launch_bounds__(256) void gemm_bf16(
    const ushort* __restrict__ A, const ushort* __restrict__ Bt, ushort* __restrict__ C,
    int M, int K, int N) {
    constexpr int LD = 40;                 // bf16 elems per LDS row (32 + 8 pad) -> 80B stride
    __shared__ ushort As[128 * LD];
    __shared__ ushort Bs[128 * LD];
    const int tid = threadIdx.x;
    const long long bm = blockIdx.x * 128LL;
    const int bn = blockIdx.y * 128;
    const int lane = tid & 63, wave = tid >> 6;
    const int mo = (wave & 1) * 64, no = (wave >> 1) * 64;
    const int l15 = lane & 15, quad = lane >> 4;
    floatx4 acc[4][4] = {};

    for (int k0 = 0; k0 < K; k0 += 32) {
        // stage 128x32 bf16 tiles of A and Bt (512 chunks of 16B each; 2 per thread)
#pragma unroll
        for (int t = 0; t < 2; ++t) {
            int ch = tid + t * 256;
            int r = ch >> 2, c = ch & 3;
            float4 av = make_float4(0.f, 0.f, 0.f, 0.f);
            if (bm + r < M) av = *(const float4*)(A + (size_t)(bm + r) * K + k0 + c * 8);
            *(float4*)(As + r * LD + c * 8) = av;
            float4 bv = *(const float4*)(Bt + (size_t)(bn + r) * K + k0 + c * 8);
            *(float4*)(Bs + r * LD + c * 8) = bv;
        }
        __syncthreads();
        bf16x8 af[4], bfr[4];
#pragma unroll
        for (int mt = 0; mt < 4; ++mt)
            af[mt] = *(const bf16x8*)(As + (mo + mt * 16 + l15) * LD + quad * 8);
#pragma unroll
        for (int nt = 0; nt < 4; ++nt)
            bfr[nt] = *(const bf16x8*)(Bs + (no + nt * 16 + l15) * LD + quad * 8);
#pragma unroll
        for (int mt = 0; mt < 4; ++mt)
#pragma unroll
            for (int nt = 0; nt < 4; ++nt)
                acc[mt][nt] = __builtin_amdgcn_mfma_f32_16x16x32_bf16(af[mt], bfr[nt], acc[mt][nt], 0, 0, 0);
        __syncthreads();
    }
    // epilogue: C/D layout col=lane&15, row=quad*4+reg
#pragma unroll
    for (int mt = 0; mt < 4; ++mt)
#pragma unroll
        for (int i = 0; i < 4; ++i) {
            long long row = bm + mo + mt * 16 + quad * 4 + i;
            if (row < M) {
#pragma unroll
                for (int nt = 0; nt < 4; ++nt)
                    C[row * (size_t)N + bn + no + nt * 16 + l15] = f2bf(acc[mt][nt][i]);
            }
        }
}

// ---------------- scatter-mean from bf16 y: agg[dst] += y[src, yoff:]*invdeg[dst] ----------------
// one thread per (edge, 8-elem chunk); lc = log2(F/8)
__global__ void scatter_mean_bf(const ushort* __restrict__ y, int ystride, int yoff,
                                const int* __restrict__ src, const int* __restrict__ dst,
                                const float* __restrict__ invdeg, float* __restrict__ agg,
                                int F, int lc, long long nwork) {
    long long i = blockIdx.x * 256LL + threadIdx.x;
    if (i >= nwork) return;
    int e = (int)(i >> lc);
    int c = (int)(i & ((1 << lc) - 1));
    int s = src[e], d = dst[e];
    uint4 v = *(const uint4*)(y + (size_t)s * ystride + yoff + c * 8);
    float w = invdeg[d];
    float* p = agg + (size_t)d * F + c * 8;
    atomicAdd(p + 0, __uint_as_float(v.x << 16) * w);
    atomicAdd(p + 1, __uint_as_float(v.x & 0xffff0000u) * w);
    atomicAdd(p + 2, __uint_as_float(v.y << 16) * w);
    atomicAdd(p + 3, __uint_as_float(v.y & 0xffff0000u) * w);
    atomicAdd(p + 4, __uint_as_float(v.z << 16) * w);
    atomicAdd(p + 5, __uint_as_float(v.z & 0xffff0000u) * w);
    atomicAdd(p + 6, __uint_as_float(v.w << 16) * w);
    atomicAdd(p + 7, __uint_as_float(v.w & 0xffff0000u) * w);
}

// ---------------- combine: relu(agg + y_loop + bias); bf16 out (layer1) ----------------
__global__ void combine_relu_bf(const float* __restrict__ agg, const ushort* __restrict__ y,
                                int ystride, int yoff, const float* __restrict__ bias,
                                ushort* __restrict__ hout, int F, int lc, long long nw) {
    long long i = blockIdx.x * 256LL + threadIdx.x;
    if (i >= nw) return;
    int node = (int)(i >> lc);
    int c = (int)(i & ((1 << lc) - 1)) << 2;
    float4 a = *(const float4*)(agg + (size_t)node * F + c);
    ushort4 l = *(const ushort4*)(y + (size_t)node * ystride + yoff + c);
    ushort4 r;
    r.x = f2bf(fmaxf(a.x + bf2f(l.x) + bias[c + 0], 0.f));
    r.y = f2bf(fmaxf(a.y + bf2f(l.y) + bias[c + 1], 0.f));
    r.z = f2bf(fmaxf(a.z + bf2f(l.z) + bias[c + 2], 0.f));
    r.w = f2bf(fmaxf(a.w + bf2f(l.w) + bias[c + 3], 0.f));
    *(ushort4*)(hout + (size_t)node * F + c) = r;
}

// fp32 out, in place over agg (layer2)
__global__ void combine_relu_f32(float* __restrict__ agg, const ushort* __restrict__ y,
                                 int ystride, int yoff, const float* __restrict__ bias,
                                 int F, int lc, long long nw) {
    long long i = blockIdx.x * 256LL + threadIdx.x;
    if (i >= nw) return;
    int node = (int)(i >> lc);
    int c = (int)(i & ((1 << lc) - 1)) << 2;
    float4 a = *(float4*)(agg + (size_t)node * F + c);
    ushort4 l = *(const ushort4*)(y + (size_t)node * ystride + yoff + c);
    a.x = fmaxf(a.x + bf2f(l.x) + bias[c + 0], 0.f);
    a.y = fmaxf(a.y + bf2f(l.y) + bias[c + 1], 0.f);
    a.z = fmaxf(a.z + bf2f(l.z) + bias[c + 2], 0.f);
    a.w = fmaxf(a.w + bf2f(l.w) + bias[c + 3], 0.f);
    *(float4*)(agg + (size_t)node * F + c) = a;
}

__global__ void init_out(float* __restrict__ out, const float* __restrict__ b, int G) {
    int i = threadIdx.x;
    if (i < G) out[i] = b[0];
}

// one wave per node: s = dot(h[node], w); LDS-bin by gid; flush per block
__global__ void score_reduce(const float* __restrict__ h, const float* __restrict__ w,
                             const int* __restrict__ gid, int F, int n_nodes,
                             float* __restrict__ out, int G) {
    __shared__ float part[64];
    for (int i = threadIdx.x; i < 64; i += blockDim.x) part[i] = 0.f;
    __syncthreads();
    int lane = threadIdx.x & 63;
    int wavesPerBlock = blockDim.x >> 6;
    int wave = blockIdx.x * wavesPerBlock + (threadIdx.x >> 6);
    int nwaves = gridDim.x * wavesPerBlock;
    for (int node = wave; node < n_nodes; node += nwaves) {
        float s = 0.f;
        for (int f = lane; f < F; f += 64) s += h[(size_t)node * F + f] * w[f];
#pragma unroll
        for (int off = 32; off; off >>= 1) s += __shfl_down(s, off);
        if (lane == 0) atomicAdd(&part[gid[node]], s);
    }
    __syncthreads();
    for (int i = threadIdx.x; i < G; i += blockDim.x)
        atomicAdd(&out[i], part[i]);
}

// ---------------- launch ----------------

extern "C" void kernel_launch(void* const* d_in, const int* in_sizes, int n_in,
                              void* d_out, int out_size, void* d_ws, size_t ws_size,
                              hipStream_t stream) {
    const float* x_sent = (const float*)d_in[0];
    const float* x_doc  = (const float*)d_in[1];
    const float* coeff1 = (const float*)d_in[2];
    const float* basis1 = (const float*)d_in[3];
    const float* loopw1 = (const float*)d_in[4];
    const float* bias1  = (const float*)d_in[5];
    const float* coeff2 = (const float*)d_in[6];
    const float* basis2 = (const float*)d_in[7];
    const float* loopw2 = (const float*)d_in[8];
    const float* bias2  = (const float*)d_in[9];
    const float* wscore = (const float*)d_in[10];
    const float* bscore = (const float*)d_in[11];
    const int* src_ss = (const int*)d_in[12];
    const int* dst_ss = (const int*)d_in[13];
    const int* src_sd = (const int*)d_in[14];
    const int* dst_sd = (const int*)d_in[15];
    const int* src_ds = (const int*)d_in[16];
    const int* dst_ds = (const int*)d_in[17];
    const int* gid_sent = (const int*)d_in[18];
    const int* gid_doc  = (const int*)d_in[19];

    const int DIN = 768, DH = 256, DOo = 128;
    const int NS = in_sizes[0] / DIN;     // 100000
    const int ND = in_sizes[1] / DIN;     // 10000
    const int E_SS = in_sizes[12], E_SD = in_sizes[14], E_DS = in_sizes[16];
    const int G = out_size;               // 32
    float* out = (float*)d_out;

    // ---- workspace layout (bytes, 256B aligned blocks) ----
    char* base = (char*)d_ws;
    size_t off = 0;
    auto alloc = [&](size_t bytes) -> char* {
        char* p = base + off;
        off = (off + bytes + 255) & ~(size_t)255;
        return p;
    };
    ushort* B1sT = (ushort*)alloc((size_t)768 * 768 * 2);   // [3*DH rows][768 K]
    ushort* B1dT = (ushort*)alloc((size_t)512 * 768 * 2);   // [2*DH rows][768 K]
    ushort* B2sT = (ushort*)alloc((size_t)384 * 256 * 2);   // [3*DOo rows][256 K]
    ushort* B2dT = (ushort*)alloc((size_t)256 * 256 * 2);
    float* invdeg_ss = (float*)alloc(((size_t)NS + NS + ND) * 4);
    float* invdeg_ds = invdeg_ss + NS;
    float* invdeg_sd = invdeg_ds + NS;
    // P1: xs_bf/xd_bf, reused for h1 bf16 after gemm1
    ushort* xs_bf = (ushort*)alloc((size_t)NS * 768 * 2);
    ushort* xd_bf = (ushort*)alloc((size_t)ND * 768 * 2);
    ushort* h1s_bf = xs_bf;                                  // NS*256, dead xs_bf after gemm1
    ushort* h1d_bf = xs_bf + (size_t)NS * 256;               // ND*256
    // P2: ys1/yd1 (bf16), reused for ys2/yd2
    ushort* ys1 = (ushort*)alloc((size_t)NS * 768 * 2);
    ushort* yd1 = (ushort*)alloc((size_t)ND * 512 * 2);
    ushort* ys2 = ys1;                                       // NS*384
    ushort* yd2 = ys1 + (size_t)NS * 384;                    // ND*256
    // P3: agg fp32, reused for layer2 agg
    float* aggs = (float*)alloc(((size_t)NS + ND) * 256 * 4);
    float* aggd = aggs + (size_t)NS * 256;
    float* aggs2 = aggs;                                     // NS*128
    float* aggd2 = aggs + (size_t)NS * 128;                  // ND*128

    // ---- build transposed bf16 weights ----
    long long t1 = (long long)768 * DH;    // per-block elems layer1 (K*N = 768*256)
    long long t2 = (long long)256 * DOo;   // layer2 (256*128)
    long long KN1 = (long long)768 * DH;   // basis1 slice size
    long long KN2 = (long long)256 * DOo;
    int bt1 = (int)CDIV(t1, 256), bt2 = (int)CDIV(t2, 256);
    fill_basis_T<<<bt1, 256, 0, stream>>>(B1sT, 768, 0,       basis1, KN1, coeff1, 0, DH, t1);
    fill_basis_T<<<bt1, 256, 0, stream>>>(B1sT, 768, DH,      basis1, KN1, coeff1, 2, DH, t1);
    fill_copy_T <<<bt1, 256, 0, stream>>>(B1sT, 768, 2 * DH,  loopw1, DH, t1);
    fill_basis_T<<<bt1, 256, 0, stream>>>(B1dT, 768, 0,       basis1, KN1, coeff1, 1, DH, t1);
    fill_copy_T <<<bt1, 256, 0, stream>>>(B1dT, 768, DH,      loopw1, DH, t1);
    fill_basis_T<<<bt2, 256, 0, stream>>>(B2sT, 256, 0,        basis2, KN2, coeff2, 0, DOo, t2);
    fill_basis_T<<<bt2, 256, 0, stream>>>(B2sT, 256, DOo,      basis2, KN2, coeff2, 2, DOo, t2);
    fill_copy_T <<<bt2, 256, 0, stream>>>(B2sT, 256, 2 * DOo,  loopw2, DOo, t2);
    fill_basis_T<<<bt2, 256, 0, stream>>>(B2dT, 256, 0,        basis2, KN2, coeff2, 1, DOo, t2);
    fill_copy_T <<<bt2, 256, 0, stream>>>(B2dT, 256, DOo,      loopw2, DOo, t2);

    // ---- convert inputs to bf16 ----
    cvt_bf16_k<<<(int)CDIV((long long)NS * 768 / 8, 256), 256, 0, stream>>>(
        (const float4*)x_sent, (uint4*)xs_bf, (long long)NS * 768 / 8);
    cvt_bf16_k<<<(int)CDIV((long long)ND * 768 / 8, 256), 256, 0, stream>>>(
        (const float4*)x_doc, (uint4*)xd_bf, (long long)ND * 768 / 8);

    // ---- degrees (shared by both layers) ----
    long long ndeg = (long long)NS + NS + ND;
    zero_f4<<<(int)CDIV(ndeg / 4, 256), 256, 0, stream>>>((float4*)invdeg_ss, ndeg / 4);
    accum_deg<<<CDIV(E_SS, 256), 256, 0, stream>>>(dst_ss, E_SS, invdeg_ss);
    accum_deg<<<CDIV(E_DS, 256), 256, 0, stream>>>(dst_ds, E_DS, invdeg_ds);
    accum_deg<<<CDIV(E_SD, 256), 256, 0, stream>>>(dst_sd, E_SD, invdeg_sd);
    invert_deg<<<(int)CDIV(ndeg, 256), 256, 0, stream>>>(invdeg_ss, (int)ndeg);

    // ---- layer 1 GEMMs ----
    {
        dim3 g(CDIV(NS, 128), (3 * DH) / 128);
        gemm_bf16<<<g, 256, 0, stream>>>(xs_bf, B1sT, ys1, NS, 768, 3 * DH);
    }
    {
        dim3 g(CDIV(ND, 128), (2 * DH) / 128);
        gemm_bf16<<<g, 256, 0, stream>>>(xd_bf, B1dT, yd1, ND, 768, 2 * DH);
    }

    // ---- layer 1 aggregation ----
    long long nagg1 = ((long long)NS + ND) * DH;
    zero_f4<<<(int)CDIV(nagg1 / 4, 256), 256, 0, stream>>>((float4*)aggs, nagg1 / 4);
    scatter_mean_bf<<<(int)CDIV((long long)E_SD * 32, 256), 256, 0, stream>>>(
        ys1, 3 * DH, 0, src_sd, dst_sd, invdeg_sd, aggd, DH, 5, (long long)E_SD * 32);
    scatter_mean_bf<<<(int)CDIV((long long)E_DS * 32, 256), 256, 0, stream>>>(
        yd1, 2 * DH, 0, src_ds, dst_ds, invdeg_ds, aggs, DH, 5, (long long)E_DS * 32);
    scatter_mean_bf<<<(int)CDIV((long long)E_SS * 32, 256), 256, 0, stream>>>(
        ys1, 3 * DH, DH, src_ss, dst_ss, invdeg_ss, aggs, DH, 5, (long long)E_SS * 32);
    combine_relu_bf<<<(int)CDIV((long long)NS * 64, 256), 256, 0, stream>>>(
        aggs, ys1, 3 * DH, 2 * DH, bias1, h1s_bf, DH, 6, (long long)NS * 64);
    combine_relu_bf<<<(int)CDIV((long long)ND * 64, 256), 256, 0, stream>>>(
        aggd, yd1, 2 * DH, DH, bias1, h1d_bf, DH, 6, (long long)ND * 64);

    // ---- layer 2 GEMMs ----
    {
        dim3 g(CDIV(NS, 128), (3 * DOo) / 128);
        gemm_bf16<<<g, 256, 0, stream>>>(h1s_bf, B2sT, ys2, NS, 256, 3 * DOo);
    }
    {
        dim3 g(CDIV(ND, 128), (2 * DOo) / 128);
        gemm_bf16<<<g, 256, 0, stream>>>(h1d_bf, B2dT, yd2, ND, 256, 2 * DOo);
    }

    // ---- layer 2 aggregation ----
    long long nagg2 = ((long long)NS + ND) * DOo;
    zero_f4<<<(int)CDIV(nagg2 / 4, 256), 256, 0, stream>>>((float4*)aggs2, nagg2 / 4);
    scatter_mean_bf<<<(int)CDIV((long long)E_SD * 16, 256), 256, 0, stream>>>(
        ys2, 3 * DOo, 0, src_sd, dst_sd, invdeg_sd, aggd2, DOo, 4, (long long)E_SD * 16);
    scatter_mean_bf<<<(int)CDIV((long long)E_DS * 16, 256), 256, 0, stream>>>(
        yd2, 2 * DOo, 0, src_ds, dst_ds, invdeg_ds, aggs2, DOo, 4, (long long)E_DS * 16);
    scatter_mean_bf<<<(int)CDIV((long long)E_SS * 16, 256), 256, 0, stream>>>(
        ys2, 3 * DOo, DOo, src_ss, dst_ss, invdeg_ss, aggs2, DOo, 4, (long long)E_SS * 16);
    combine_relu_f32<<<(int)CDIV((long long)NS * 32, 256), 256, 0, stream>>>(
        aggs2, ys2, 3 * DOo, 2 * DOo, bias2, DOo, 5, (long long)NS * 32);
    combine_relu_f32<<<(int)CDIV((long long)ND * 32, 256), 256, 0, stream>>>(
        aggd2, yd2, 2 * DOo, DOo, bias2, DOo, 5, (long long)ND * 32);

    // ---- readout ----
    init_out<<<1, 64, 0, stream>>>(out, bscore, G);
    score_reduce<<<512, 256, 0, stream>>>(aggs2, wscore, gid_sent, DOo, NS, out, G);
    score_reduce<<<128, 256, 0, stream>>>(aggd2, wscore, gid_doc, DOo, ND, out, G);
}

// Round 3
// 1203.483 us; speedup vs baseline: 6.0897x; 6.0897x over previous
//
#include <hip/hip_runtime.h>

#define CDIV(a,b) (((a)+(b)-1)/(b))

typedef __attribute__((ext_vector_type(8))) short bf16x8;
typedef __attribute__((ext_vector_type(4))) float floatx4;

__device__ __forceinline__ ushort f2bf(float x) {
    unsigned u = __float_as_uint(x);
    return (ushort)((u + 0x7fffu + ((u >> 16) & 1u)) >> 16);   // RNE
}
__device__ __forceinline__ float bflo(unsigned v) { return __uint_as_float(v << 16); }
__device__ __forceinline__ float bfhi(unsigned v) { return __uint_as_float(v & 0xffff0000u); }

// ---------------- utility kernels ----------------

__global__ void zero_f4(float4* __restrict__ p, long long n4) {
    long long i = blockIdx.x * 256LL + threadIdx.x;
    if (i < n4) p[i] = make_float4(0.f, 0.f, 0.f, 0.f);
}

__global__ void cvt_bf16_k(const float4* __restrict__ in, uint4* __restrict__ out, long long n8) {
    long long i = blockIdx.x * 256LL + threadIdx.x;
    if (i >= n8) return;
    float4 a = in[2 * i], b = in[2 * i + 1];
    uint4 o;
    o.x = (unsigned)f2bf(a.x) | ((unsigned)f2bf(a.y) << 16);
    o.y = (unsigned)f2bf(a.z) | ((unsigned)f2bf(a.w) << 16);
    o.z = (unsigned)f2bf(b.x) | ((unsigned)f2bf(b.y) << 16);
    o.w = (unsigned)f2bf(b.z) | ((unsigned)f2bf(b.w) << 16);
    out[i] = o;
}

// Bt[(col0+n)*K + k] = c0*basis[k*N+n] + c1*basis[KN + k*N+n]   (bf16 out, transposed)
__global__ void fill_basis_T(ushort* __restrict__ out, int K, int col0,
                             const float* __restrict__ basis, long long KN,
                             const float* __restrict__ coeff, int r, int N, long long total) {
    long long i = blockIdx.x * 256LL + threadIdx.x;
    if (i >= total) return;
    int k = (int)(i % K), n = (int)(i / K);
    float c0 = coeff[2 * r], c1 = coeff[2 * r + 1];
    out[(size_t)(col0 + n) * K + k] = f2bf(c0 * basis[(size_t)k * N + n] + c1 * basis[KN + (size_t)k * N + n]);
}

__global__ void fill_copy_T(ushort* __restrict__ out, int K, int col0,
                            const float* __restrict__ src, int N, long long total) {
    long long i = blockIdx.x * 256LL + threadIdx.x;
    if (i >= total) return;
    int k = (int)(i % K), n = (int)(i / K);
    out[(size_t)(col0 + n) * K + k] = f2bf(src[(size_t)k * N + n]);
}

// ---------------- CSR build ----------------

__global__ void accum_deg_i(const int* __restrict__ dst, int n, int slot, int* __restrict__ deg) {
    int i = blockIdx.x * 256 + threadIdx.x;
    if (i < n) atomicAdd(&deg[slot + dst[i]], 1);
}

__global__ void scan_p1(const int* __restrict__ deg, int n, int* __restrict__ bsum) {
    __shared__ int sd[256];
    int blk = blockIdx.x, tid = threadIdx.x;
    int i0 = blk * 1024 + tid * 4;
    int s = 0;
#pragma unroll
    for (int j = 0; j < 4; ++j) if (i0 + j < n) s += deg[i0 + j];
    sd[tid] = s; __syncthreads();
    for (int o = 128; o; o >>= 1) {
        if (tid < o) sd[tid] += sd[tid + o];
        __syncthreads();
    }
    if (tid == 0) bsum[blk] = sd[0];
}

// single block: exclusive scan of bsum[nb] (nb <= 256); also write rowptr[ntot]=etot
__global__ void scan_p2(int* __restrict__ bsum, int nb, int* __restrict__ rowptr, int ntot, int etot) {
    __shared__ int sd[256];
    int tid = threadIdx.x;
    int v = (tid < nb) ? bsum[tid] : 0;
    sd[tid] = v; __syncthreads();
    for (int o = 1; o < 256; o <<= 1) {
        int t = (tid >= o) ? sd[tid - o] : 0;
        __syncthreads();
        sd[tid] += t;
        __syncthreads();
    }
    if (tid < nb) bsum[tid] = sd[tid] - v;   // exclusive
    if (tid == 0) rowptr[ntot] = etot;
}

__global__ void scan_p3(const int* __restrict__ deg, int n, const int* __restrict__ bsum,
                        int* __restrict__ rowptr) {
    __shared__ int sd[256];
    int blk = blockIdx.x, tid = threadIdx.x;
    int i0 = blk * 1024 + tid * 4;
    int v[4]; int s = 0;
#pragma unroll
    for (int j = 0; j < 4; ++j) { v[j] = (i0 + j < n) ? deg[i0 + j] : 0; s += v[j]; }
    sd[tid] = s; __syncthreads();
    for (int o = 1; o < 256; o <<= 1) {
        int t = (tid >= o) ? sd[tid - o] : 0;
        __syncthreads();
        sd[tid] += t;
        __syncthreads();
    }
    int excl = bsum[blk] + sd[tid] - s;
#pragma unroll
    for (int j = 0; j < 4; ++j) {
        if (i0 + j < n) rowptr[i0 + j] = excl;
        excl += v[j];
    }
}

__global__ void fill_csr(const int* __restrict__ src, const int* __restrict__ dst, int n, int slot,
                         const int* __restrict__ rowptr, int* __restrict__ fill, int* __restrict__ col) {
    int i = blockIdx.x * 256 + threadIdx.x;
    if (i >= n) return;
    int d = slot + dst[i];
    int p = rowptr[d] + atomicAdd(&fill[d], 1);
    col[p] = src[i];
}

// ---------------- MFMA GEMM: C[M,N] bf16 = A[M,K] bf16 @ Bt[N,K]^T ----------------
__global__ __launch_bounds__(256) void gemm_bf16(
    const ushort* __restrict__ A, const ushort* __restrict__ Bt, ushort* __restrict__ C,
    int M, int K, int N) {
    constexpr int LD = 40;
    __shared__ ushort As[128 * LD];
    __shared__ ushort Bs[128 * LD];
    const int tid = threadIdx.x;
    const long long bm = blockIdx.x * 128LL;
    const int bn = blockIdx.y * 128;
    const int lane = tid & 63, wave = tid >> 6;
    const int mo = (wave & 1) * 64, no = (wave >> 1) * 64;
    const int l15 = lane & 15, quad = lane >> 4;
    floatx4 acc[4][4] = {};

    for (int k0 = 0; k0 < K; k0 += 32) {
#pragma unroll
        for (int t = 0; t < 2; ++t) {
            int ch = tid + t * 256;
            int r = ch >> 2, c = ch & 3;
            float4 av = make_float4(0.f, 0.f, 0.f, 0.f);
            if (bm + r < M) av = *(const float4*)(A + (size_t)(bm + r) * K + k0 + c * 8);
            *(float4*)(As + r * LD + c * 8) = av;
            float4 bv = *(const float4*)(Bt + (size_t)(bn + r) * K + k0 + c * 8);
            *(float4*)(Bs + r * LD + c * 8) = bv;
        }
        __syncthreads();
        bf16x8 af[4], bfr[4];
#pragma unroll
        for (int mt = 0; mt < 4; ++mt)
            af[mt] = *(const bf16x8*)(As + (mo + mt * 16 + l15) * LD + quad * 8);
#pragma unroll
        for (int nt = 0; nt < 4; ++nt)
            bfr[nt] = *(const bf16x8*)(Bs + (no + nt * 16 + l15) * LD + quad * 8);
#pragma unroll
        for (int mt = 0; mt < 4; ++mt)
#pragma unroll
            for (int nt = 0; nt < 4; ++nt)
                acc[mt][nt] = __builtin_amdgcn_mfma_f32_16x16x32_bf16(af[mt], bfr[nt], acc[mt][nt], 0, 0, 0);
        __syncthreads();
    }
#pragma unroll
    for (int mt = 0; mt < 4; ++mt)
#pragma unroll
        for (int i = 0; i < 4; ++i) {
            long long row = bm + mo + mt * 16 + quad * 4 + i;
            if (row < M) {
#pragma unroll
                for (int nt = 0; nt < 4; ++nt)
                    C[row * (size_t)N + bn + no + nt * 16 + l15] = f2bf(acc[mt][nt][i]);
            }
        }
}

// ---------------- fused gather layer kernels ----------------
// Layer 1, sent dst: h1s[d] = relu(mean_ss(ys1[:,256:512]) + mean_ds(yd1[:,0:256])
//                                 + ys1[d,512:768] + bias)   -> bf16 [NS][256]
__global__ __launch_bounds__(256) void fused_sent_l1(
    const ushort* __restrict__ ys, const ushort* __restrict__ yd,
    const int* __restrict__ rowptr, const int* __restrict__ col,
    const float* __restrict__ bias, ushort* __restrict__ hout, int NS) {
    int d = blockIdx.x * 4 + (threadIdx.x >> 6);
    if (d >= NS) return;
    int lane = threadIdx.x & 63;
    int cb = lane * 4;
    float a0 = 0, a1 = 0, a2 = 0, a3 = 0;
    int s0 = rowptr[d], s1 = rowptr[d + 1];
    for (int e = s0; e < s1; ++e) {
        int s = col[e];
        uint2 v = *(const uint2*)(ys + (size_t)s * 768 + 256 + cb);
        a0 += bflo(v.x); a1 += bfhi(v.x); a2 += bflo(v.y); a3 += bfhi(v.y);
    }
    float inv = 1.f / (float)max(s1 - s0, 1);
    float m0 = a0 * inv, m1 = a1 * inv, m2 = a2 * inv, m3 = a3 * inv;
    a0 = a1 = a2 = a3 = 0.f;
    int t0 = rowptr[NS + d], t1 = rowptr[NS + d + 1];
    for (int e = t0; e < t1; ++e) {
        int s = col[e];
        uint2 v = *(const uint2*)(yd + (size_t)s * 512 + cb);
        a0 += bflo(v.x); a1 += bfhi(v.x); a2 += bflo(v.y); a3 += bfhi(v.y);
    }
    inv = 1.f / (float)max(t1 - t0, 1);
    uint2 lv = *(const uint2*)(ys + (size_t)d * 768 + 512 + cb);
    float h0 = fmaxf(m0 + a0 * inv + bflo(lv.x) + bias[cb + 0], 0.f);
    float h1 = fmaxf(m1 + a1 * inv + bfhi(lv.x) + bias[cb + 1], 0.f);
    float h2 = fmaxf(m2 + a2 * inv + bflo(lv.y) + bias[cb + 2], 0.f);
    float h3 = fmaxf(m3 + a3 * inv + bfhi(lv.y) + bias[cb + 3], 0.f);
    uint2 o;
    o.x = (unsigned)f2bf(h0) | ((unsigned)f2bf(h1) << 16);
    o.y = (unsigned)f2bf(h2) | ((unsigned)f2bf(h3) << 16);
    *(uint2*)(hout + (size_t)d * 256 + cb) = o;
}

// Layer 1, doc dst: h1d[d] = relu(mean_sd(ys1[:,0:256]) + yd1[d,256:512] + bias) -> bf16 [ND][256]
__global__ __launch_bounds__(256) void fused_doc_l1(
    const ushort* __restrict__ ys, const ushort* __restrict__ yd,
    const int* __restrict__ rowptr, const int* __restrict__ col,
    const float* __restrict__ bias, ushort* __restrict__ hout, int NS, int ND) {
    int d = blockIdx.x * 4 + (threadIdx.x >> 6);
    if (d >= ND) return;
    int lane = threadIdx.x & 63;
    int cb = lane * 4;
    float a0 = 0, a1 = 0, a2 = 0, a3 = 0;
    int s0 = rowptr[2 * NS + d], s1 = rowptr[2 * NS + d + 1];
    for (int e = s0; e < s1; ++e) {
        int s = col[e];
        uint2 v = *(const uint2*)(ys + (size_t)s * 768 + cb);
        a0 += bflo(v.x); a1 += bfhi(v.x); a2 += bflo(v.y); a3 += bfhi(v.y);
    }
    float inv = 1.f / (float)max(s1 - s0, 1);
    uint2 lv = *(const uint2*)(yd + (size_t)d * 512 + 256 + cb);
    float h0 = fmaxf(a0 * inv + bflo(lv.x) + bias[cb + 0], 0.f);
    float h1 = fmaxf(a1 * inv + bfhi(lv.x) + bias[cb + 1], 0.f);
    float h2 = fmaxf(a2 * inv + bflo(lv.y) + bias[cb + 2], 0.f);
    float h3 = fmaxf(a3 * inv + bfhi(lv.y) + bias[cb + 3], 0.f);
    uint2 o;
    o.x = (unsigned)f2bf(h0) | ((unsigned)f2bf(h1) << 16);
    o.y = (unsigned)f2bf(h2) | ((unsigned)f2bf(h3) << 16);
    *(uint2*)(hout + (size_t)d * 256 + cb) = o;
}

// Layer 2, sent dst, fused with readout: out[gid[d]] += dot(h2_sent[d], w)
__global__ __launch_bounds__(256) void fused_sent_l2(
    const ushort* __restrict__ ys, const ushort* __restrict__ yd,
    const int* __restrict__ rowptr, const int* __restrict__ col,
    const float* __restrict__ bias, const float* __restrict__ w,
    const int* __restrict__ gid, float* __restrict__ out, int NS, int G) {
    __shared__ float part[4][32];
    const int tid = threadIdx.x;
    const int lane = tid & 63, wv = tid >> 6;
    const int cb = lane * 2;
    float racc = 0.f;
    const int nw = gridDim.x * 4;
    for (int d = blockIdx.x * 4 + wv; d < NS; d += nw) {
        float a0 = 0.f, a1 = 0.f;
        int s0 = rowptr[d], s1 = rowptr[d + 1];
        for (int e = s0; e < s1; ++e) {
            int s = col[e];
            unsigned v = *(const unsigned*)(ys + (size_t)s * 384 + 128 + cb);
            a0 += bflo(v); a1 += bfhi(v);
        }
        float inv = 1.f / (float)max(s1 - s0, 1);
        float m0 = a0 * inv, m1 = a1 * inv;
        a0 = 0.f; a1 = 0.f;
        int t0 = rowptr[NS + d], t1 = rowptr[NS + d + 1];
        for (int e = t0; e < t1; ++e) {
            int s = col[e];
            unsigned v = *(const unsigned*)(yd + (size_t)s * 256 + cb);
            a0 += bflo(v); a1 += bfhi(v);
        }
        inv = 1.f / (float)max(t1 - t0, 1);
        unsigned lv = *(const unsigned*)(ys + (size_t)d * 384 + 256 + cb);
        float h0 = fmaxf(m0 + a0 * inv + bflo(lv) + bias[cb + 0], 0.f);
        float h1 = fmaxf(m1 + a1 * inv + bfhi(lv) + bias[cb + 1], 0.f);
        float sc = h0 * w[cb] + h1 * w[cb + 1];
#pragma unroll
        for (int o = 32; o; o >>= 1) sc += __shfl_down(sc, o);
        sc = __shfl(sc, 0);
        if (lane == gid[d]) racc += sc;
    }
    if (lane < 32) part[wv][lane] = racc;
    __syncthreads();
    if (tid < G) atomicAdd(&out[tid], part[0][tid] + part[1][tid] + part[2][tid] + part[3][tid]);
}

// Layer 2, doc dst, fused with readout
__global__ __launch_bounds__(256) void fused_doc_l2(
    const ushort* __restrict__ ys, const ushort* __restrict__ yd,
    const int* __restrict__ rowptr, const int* __restrict__ col,
    const float* __restrict__ bias, const float* __restrict__ w,
    const int* __restrict__ gid, float* __restrict__ out, int NS, int ND, int G) {
    __shared__ float part[4][32];
    const int tid = threadIdx.x;
    const int lane = tid & 63, wv = tid >> 6;
    const int cb = lane * 2;
    float racc = 0.f;
    const int nw = gridDim.x * 4;
    for (int d = blockIdx.x * 4 + wv; d < ND; d += nw) {
        float a0 = 0.f, a1 = 0.f;
        int s0 = rowptr[2 * NS + d], s1 = rowptr[2 * NS + d + 1];
        for (int e = s0; e < s1; ++e) {
            int s = col[e];
            unsigned v = *(const unsigned*)(ys + (size_t)s * 384 + cb);
            a0 += bflo(v); a1 += bfhi(v);
        }
        float inv = 1.f / (float)max(s1 - s0, 1);
        unsigned lv = *(const unsigned*)(yd + (size_t)d * 256 + 128 + cb);
        float h0 = fmaxf(a0 * inv + bflo(lv) + bias[cb + 0], 0.f);
        float h1 = fmaxf(a1 * inv + bfhi(lv) + bias[cb + 1], 0.f);
        float sc = h0 * w[cb] + h1 * w[cb + 1];
#pragma unroll
        for (int o = 32; o; o >>= 1) sc += __shfl_down(sc, o);
        sc = __shfl(sc, 0);
        if (lane == gid[d]) racc += sc;
    }
    if (lane < 32) part[wv][lane] = racc;
    __syncthreads();
    if (tid < G) atomicAdd(&out[tid], part[0][tid] + part[1][tid] + part[2][tid] + part[3][tid]);
}

__global__ void init_out(float* __restrict__ out, const float* __restrict__ b, int G) {
    int i = threadIdx.x;
    if (i < G) out[i] = b[0];
}

// ---------------- launch ----------------

extern "C" void kernel_launch(void* const* d_in, const int* in_sizes, int n_in,
                              void* d_out, int out_size, void* d_ws, size_t ws_size,
                              hipStream_t stream) {
    const float* x_sent = (const float*)d_in[0];
    const float* x_doc  = (const float*)d_in[1];
    const float* coeff1 = (const float*)d_in[2];
    const float* basis1 = (const float*)d_in[3];
    const float* loopw1 = (const float*)d_in[4];
    const float* bias1  = (const float*)d_in[5];
    const float* coeff2 = (const float*)d_in[6];
    const float* basis2 = (const float*)d_in[7];
    const float* loopw2 = (const float*)d_in[8];
    const float* bias2  = (const float*)d_in[9];
    const float* wscore = (const float*)d_in[10];
    const float* bscore = (const float*)d_in[11];
    const int* src_ss = (const int*)d_in[12];
    const int* dst_ss = (const int*)d_in[13];
    const int* src_sd = (const int*)d_in[14];
    const int* dst_sd = (const int*)d_in[15];
    const int* src_ds = (const int*)d_in[16];
    const int* dst_ds = (const int*)d_in[17];
    const int* gid_sent = (const int*)d_in[18];
    const int* gid_doc  = (const int*)d_in[19];

    const int DIN = 768, DH = 256, DOo = 128;
    const int NS = in_sizes[0] / DIN;     // 100000
    const int ND = in_sizes[1] / DIN;     // 10000
    const int E_SS = in_sizes[12], E_SD = in_sizes[14], E_DS = in_sizes[16];
    const int NTOT = NS + NS + ND;        // deg slots: [0,NS)=ss, [NS,2NS)=ds, [2NS,+ND)=sd
    const int ETOT = E_SS + E_DS + E_SD;
    const int G = out_size;               // 32
    float* out = (float*)d_out;

    char* base = (char*)d_ws;
    size_t off = 0;
    auto alloc = [&](size_t bytes) -> char* {
        char* p = base + off;
        off = (off + bytes + 255) & ~(size_t)255;
        return p;
    };
    ushort* B1sT = (ushort*)alloc((size_t)768 * 768 * 2);
    ushort* B1dT = (ushort*)alloc((size_t)512 * 768 * 2);
    ushort* B2sT = (ushort*)alloc((size_t)384 * 256 * 2);
    ushort* B2dT = (ushort*)alloc((size_t)256 * 256 * 2);
    ushort* xs_bf = (ushort*)alloc((size_t)NS * 768 * 2);
    ushort* xd_bf = (ushort*)alloc((size_t)ND * 768 * 2);
    ushort* ys1 = (ushort*)alloc((size_t)NS * 768 * 2);
    ushort* yd1 = (ushort*)alloc((size_t)ND * 512 * 2);
    ushort* h1s = (ushort*)alloc((size_t)NS * 256 * 2);
    ushort* h1d = (ushort*)alloc((size_t)ND * 256 * 2);
    int* deg  = (int*)alloc((size_t)2 * NTOT * 4);   // deg + fill, zeroed jointly
    int* fill = deg + NTOT;
    int* rowptr = (int*)alloc((size_t)(NTOT + 1) * 4);
    int* bsum = (int*)alloc(256 * 4);
    int* colall = (int*)alloc((size_t)ETOT * 4);
    // layer-2 GEMM outputs alias xs_bf (dead after layer-1 GEMMs)
    ushort* ys2 = xs_bf;                        // [NS][384]
    ushort* yd2 = xs_bf + (size_t)NS * 384;     // [ND][256]

    // ---- weights (transposed bf16) ----
    long long t1 = (long long)768 * DH, t2 = (long long)256 * DOo;
    long long KN1 = t1, KN2 = t2;
    int bt1 = (int)CDIV(t1, 256), bt2 = (int)CDIV(t2, 256);
    fill_basis_T<<<bt1, 256, 0, stream>>>(B1sT, 768, 0,       basis1, KN1, coeff1, 0, DH, t1);
    fill_basis_T<<<bt1, 256, 0, stream>>>(B1sT, 768, DH,      basis1, KN1, coeff1, 2, DH, t1);
    fill_copy_T <<<bt1, 256, 0, stream>>>(B1sT, 768, 2 * DH,  loopw1, DH, t1);
    fill_basis_T<<<bt1, 256, 0, stream>>>(B1dT, 768, 0,       basis1, KN1, coeff1, 1, DH, t1);
    fill_copy_T <<<bt1, 256, 0, stream>>>(B1dT, 768, DH,      loopw1, DH, t1);
    fill_basis_T<<<bt2, 256, 0, stream>>>(B2sT, 256, 0,        basis2, KN2, coeff2, 0, DOo, t2);
    fill_basis_T<<<bt2, 256, 0, stream>>>(B2sT, 256, DOo,      basis2, KN2, coeff2, 2, DOo, t2);
    fill_copy_T <<<bt2, 256, 0, stream>>>(B2sT, 256, 2 * DOo,  loopw2, DOo, t2);
    fill_basis_T<<<bt2, 256, 0, stream>>>(B2dT, 256, 0,        basis2, KN2, coeff2, 1, DOo, t2);
    fill_copy_T <<<bt2, 256, 0, stream>>>(B2dT, 256, DOo,      loopw2, DOo, t2);

    // ---- convert inputs to bf16 ----
    cvt_bf16_k<<<(int)CDIV((long long)NS * 768 / 8, 256), 256, 0, stream>>>(
        (const float4*)x_sent, (uint4*)xs_bf, (long long)NS * 768 / 8);
    cvt_bf16_k<<<(int)CDIV((long long)ND * 768 / 8, 256), 256, 0, stream>>>(
        (const float4*)x_doc, (uint4*)xd_bf, (long long)ND * 768 / 8);

    // ---- CSR build (joint over all 3 relations) ----
    zero_f4<<<(int)CDIV(2 * NTOT / 4, 256), 256, 0, stream>>>((float4*)deg, 2 * NTOT / 4);
    accum_deg_i<<<CDIV(E_SS, 256), 256, 0, stream>>>(dst_ss, E_SS, 0,      deg);
    accum_deg_i<<<CDIV(E_DS, 256), 256, 0, stream>>>(dst_ds, E_DS, NS,     deg);
    accum_deg_i<<<CDIV(E_SD, 256), 256, 0, stream>>>(dst_sd, E_SD, 2 * NS, deg);
    int nb = CDIV(NTOT, 1024);
    scan_p1<<<nb, 256, 0, stream>>>(deg, NTOT, bsum);
    scan_p2<<<1, 256, 0, stream>>>(bsum, nb, rowptr, NTOT, ETOT);
    scan_p3<<<nb, 256, 0, stream>>>(deg, NTOT, bsum, rowptr);
    fill_csr<<<CDIV(E_SS, 256), 256, 0, stream>>>(src_ss, dst_ss, E_SS, 0,      rowptr, fill, colall);
    fill_csr<<<CDIV(E_DS, 256), 256, 0, stream>>>(src_ds, dst_ds, E_DS, NS,     rowptr, fill, colall);
    fill_csr<<<CDIV(E_SD, 256), 256, 0, stream>>>(src_sd, dst_sd, E_SD, 2 * NS, rowptr, fill, colall);

    // ---- layer 1 ----
    {
        dim3 g(CDIV(NS, 128), 768 / 128);
        gemm_bf16<<<g, 256, 0, stream>>>(xs_bf, B1sT, ys1, NS, 768, 768);
    }
    {
        dim3 g(CDIV(ND, 128), 512 / 128);
        gemm_bf16<<<g, 256, 0, stream>>>(xd_bf, B1dT, yd1, ND, 768, 512);
    }
    fused_sent_l1<<<CDIV(NS, 4), 256, 0, stream>>>(ys1, yd1, rowptr, colall, bias1, h1s, NS);
    fused_doc_l1 <<<CDIV(ND, 4), 256, 0, stream>>>(ys1, yd1, rowptr, colall, bias1, h1d, NS, ND);

    // ---- layer 2 ----
    {
        dim3 g(CDIV(NS, 128), 384 / 128);
        gemm_bf16<<<g, 256, 0, stream>>>(h1s, B2sT, ys2, NS, 256, 384);
    }
    {
        dim3 g(CDIV(ND, 128), 256 / 128);
        gemm_bf16<<<g, 256, 0, stream>>>(h1d, B2dT, yd2, ND, 256, 256);
    }
    init_out<<<1, 64, 0, stream>>>(out, bscore, G);
    fused_sent_l2<<<1024, 256, 0, stream>>>(ys2, yd2, rowptr, colall, bias2, wscore, gid_sent, out, NS, G);
    fused_doc_l2 <<<256, 256, 0, stream>>>(ys2, yd2, rowptr, colall, bias2, wscore, gid_doc, out, NS, ND, G);
}

// Round 4
// 1168.652 us; speedup vs baseline: 6.2712x; 1.0298x over previous
//
#include <hip/hip_runtime.h>

#define CDIV(a,b) (((a)+(b)-1)/(b))

typedef __attribute__((ext_vector_type(8))) short bf16x8;
typedef __attribute__((ext_vector_type(4))) float floatx4;

__device__ __forceinline__ ushort f2bf(float x) {
    unsigned u = __float_as_uint(x);
    return (ushort)((u + 0x7fffu + ((u >> 16) & 1u)) >> 16);   // RNE
}
__device__ __forceinline__ float bflo(unsigned v) { return __uint_as_float(v << 16); }
__device__ __forceinline__ float bfhi(unsigned v) { return __uint_as_float(v & 0xffff0000u); }

// async global->LDS DMA, 16B per lane; lds base must be wave-uniform
__device__ __forceinline__ void load_lds16(const ushort* g, ushort* l) {
    __builtin_amdgcn_global_load_lds(
        (const __attribute__((address_space(1))) void*)g,
        (__attribute__((address_space(3))) void*)l, 16, 0, 0);
}

// ---------------- utility kernels ----------------

__global__ void zero_f4(float4* __restrict__ p, long long n4) {
    long long i = blockIdx.x * 256LL + threadIdx.x;
    if (i < n4) p[i] = make_float4(0.f, 0.f, 0.f, 0.f);
}

__global__ void cvt_bf16_k(const float4* __restrict__ in, uint4* __restrict__ out, long long n8) {
    long long i = blockIdx.x * 256LL + threadIdx.x;
    if (i >= n8) return;
    float4 a = in[2 * i], b = in[2 * i + 1];
    uint4 o;
    o.x = (unsigned)f2bf(a.x) | ((unsigned)f2bf(a.y) << 16);
    o.y = (unsigned)f2bf(a.z) | ((unsigned)f2bf(a.w) << 16);
    o.z = (unsigned)f2bf(b.x) | ((unsigned)f2bf(b.y) << 16);
    o.w = (unsigned)f2bf(b.z) | ((unsigned)f2bf(b.w) << 16);
    out[i] = o;
}

// Bt[(col0+n)*K + k] = c0*basis[k*N+n] + c1*basis[KN + k*N+n]   (bf16 out, transposed)
__global__ void fill_basis_T(ushort* __restrict__ out, int K, int col0,
                             const float* __restrict__ basis, long long KN,
                             const float* __restrict__ coeff, int r, int N, long long total) {
    long long i = blockIdx.x * 256LL + threadIdx.x;
    if (i >= total) return;
    int k = (int)(i % K), n = (int)(i / K);
    float c0 = coeff[2 * r], c1 = coeff[2 * r + 1];
    out[(size_t)(col0 + n) * K + k] = f2bf(c0 * basis[(size_t)k * N + n] + c1 * basis[KN + (size_t)k * N + n]);
}

__global__ void fill_copy_T(ushort* __restrict__ out, int K, int col0,
                            const float* __restrict__ src, int N, long long total) {
    long long i = blockIdx.x * 256LL + threadIdx.x;
    if (i >= total) return;
    int k = (int)(i % K), n = (int)(i / K);
    out[(size_t)(col0 + n) * K + k] = f2bf(src[(size_t)k * N + n]);
}

// ---------------- CSR build ----------------

__global__ void accum_deg_i(const int* __restrict__ dst, int n, int slot, int* __restrict__ deg) {
    int i = blockIdx.x * 256 + threadIdx.x;
    if (i < n) atomicAdd(&deg[slot + dst[i]], 1);
}

__global__ void scan_p1(const int* __restrict__ deg, int n, int* __restrict__ bsum) {
    __shared__ int sd[256];
    int blk = blockIdx.x, tid = threadIdx.x;
    int i0 = blk * 1024 + tid * 4;
    int s = 0;
#pragma unroll
    for (int j = 0; j < 4; ++j) if (i0 + j < n) s += deg[i0 + j];
    sd[tid] = s; __syncthreads();
    for (int o = 128; o; o >>= 1) {
        if (tid < o) sd[tid] += sd[tid + o];
        __syncthreads();
    }
    if (tid == 0) bsum[blk] = sd[0];
}

__global__ void scan_p2(int* __restrict__ bsum, int nb, int* __restrict__ rowptr, int ntot, int etot) {
    __shared__ int sd[256];
    int tid = threadIdx.x;
    int v = (tid < nb) ? bsum[tid] : 0;
    sd[tid] = v; __syncthreads();
    for (int o = 1; o < 256; o <<= 1) {
        int t = (tid >= o) ? sd[tid - o] : 0;
        __syncthreads();
        sd[tid] += t;
        __syncthreads();
    }
    if (tid < nb) bsum[tid] = sd[tid] - v;   // exclusive
    if (tid == 0) rowptr[ntot] = etot;
}

__global__ void scan_p3(const int* __restrict__ deg, int n, const int* __restrict__ bsum,
                        int* __restrict__ rowptr) {
    __shared__ int sd[256];
    int blk = blockIdx.x, tid = threadIdx.x;
    int i0 = blk * 1024 + tid * 4;
    int v[4]; int s = 0;
#pragma unroll
    for (int j = 0; j < 4; ++j) { v[j] = (i0 + j < n) ? deg[i0 + j] : 0; s += v[j]; }
    sd[tid] = s; __syncthreads();
    for (int o = 1; o < 256; o <<= 1) {
        int t = (tid >= o) ? sd[tid - o] : 0;
        __syncthreads();
        sd[tid] += t;
        __syncthreads();
    }
    int excl = bsum[blk] + sd[tid] - s;
#pragma unroll
    for (int j = 0; j < 4; ++j) {
        if (i0 + j < n) rowptr[i0 + j] = excl;
        excl += v[j];
    }
}

__global__ void fill_csr(const int* __restrict__ src, const int* __restrict__ dst, int n, int slot,
                         const int* __restrict__ rowptr, int* __restrict__ fill, int* __restrict__ col) {
    int i = blockIdx.x * 256 + threadIdx.x;
    if (i >= n) return;
    int d = slot + dst[i];
    int p = rowptr[d] + atomicAdd(&fill[d], 1);
    col[p] = src[i];
}

// ---------------- MFMA GEMM: C[M,N] bf16 = A[M,K] bf16 @ Bt[N,K]^T ----------------
// K%32==0, N%128==0, M arbitrary. 128x128 tile, 256 thr. global_load_lds staging (m97 style).
// grid: x = N/128 (fast-varying => A-tile L2 reuse), y = ceil(M/128).
__global__ __launch_bounds__(256) void gemm_bf16(
    const ushort* __restrict__ A, const ushort* __restrict__ Bt, ushort* __restrict__ C,
    int M, int K, int N) {
    __shared__ ushort As[128 * 32];   // row-major, 64B/row, unpadded (required by lds DMA)
    __shared__ ushort Bs[128 * 32];
    const int tid = threadIdx.x;
    const int bn = blockIdx.x * 128;
    const long long bm = blockIdx.y * 128LL;
    const int lane = tid & 63, wave = tid >> 6;
    const int mo = (wave & 1) * 64, no = (wave >> 1) * 64;
    const int l15 = lane & 15, quad = lane >> 4;
    // staging geometry: call t, wave w, lane l -> row = t*64 + w*16 + l/4, elem chunk = (l%4)*8
    const int srow0 = wave * 16 + (lane >> 2);
    const int schunk = (lane & 3) * 8;
    floatx4 acc[4][4] = {};

    for (int k0 = 0; k0 < K; k0 += 32) {
#pragma unroll
        for (int t = 0; t < 2; ++t) {
            int row = t * 64 + srow0;
            long long ar = bm + row; if (ar >= M) ar = M - 1;   // clamp; masked at epilogue
            load_lds16(A + ar * (size_t)K + k0 + schunk, As + t * 2048 + wave * 512);
            load_lds16(Bt + (size_t)(bn + row) * K + k0 + schunk, Bs + t * 2048 + wave * 512);
        }
        __syncthreads();
        bf16x8 af[4], bfr[4];
#pragma unroll
        for (int mt = 0; mt < 4; ++mt)
            af[mt] = *(const bf16x8*)(As + (mo + mt * 16 + l15) * 32 + quad * 8);
#pragma unroll
        for (int nt = 0; nt < 4; ++nt)
            bfr[nt] = *(const bf16x8*)(Bs + (no + nt * 16 + l15) * 32 + quad * 8);
#pragma unroll
        for (int mt = 0; mt < 4; ++mt)
#pragma unroll
            for (int nt = 0; nt < 4; ++nt)
                acc[mt][nt] = __builtin_amdgcn_mfma_f32_16x16x32_bf16(af[mt], bfr[nt], acc[mt][nt], 0, 0, 0);
        __syncthreads();
    }
#pragma unroll
    for (int mt = 0; mt < 4; ++mt)
#pragma unroll
        for (int i = 0; i < 4; ++i) {
            long long row = bm + mo + mt * 16 + quad * 4 + i;
            if (row < M) {
#pragma unroll
                for (int nt = 0; nt < 4; ++nt)
                    C[row * (size_t)N + bn + no + nt * 16 + l15] = f2bf(acc[mt][nt][i]);
            }
        }
}

// ---------------- fused gather layer kernels ----------------

__global__ __launch_bounds__(256) void fused_sent_l1(
    const ushort* __restrict__ ys, const ushort* __restrict__ yd,
    const int* __restrict__ rowptr, const int* __restrict__ col,
    const float* __restrict__ bias, ushort* __restrict__ hout, int NS) {
    int d = blockIdx.x * 4 + (threadIdx.x >> 6);
    if (d >= NS) return;
    int lane = threadIdx.x & 63;
    int cb = lane * 4;
    float a0 = 0, a1 = 0, a2 = 0, a3 = 0;
    int s0 = rowptr[d], s1 = rowptr[d + 1];
    for (int e = s0; e < s1; ++e) {
        int s = col[e];
        uint2 v = *(const uint2*)(ys + (size_t)s * 768 + 256 + cb);
        a0 += bflo(v.x); a1 += bfhi(v.x); a2 += bflo(v.y); a3 += bfhi(v.y);
    }
    float inv = 1.f / (float)max(s1 - s0, 1);
    float m0 = a0 * inv, m1 = a1 * inv, m2 = a2 * inv, m3 = a3 * inv;
    a0 = a1 = a2 = a3 = 0.f;
    int t0 = rowptr[NS + d], t1 = rowptr[NS + d + 1];
    for (int e = t0; e < t1; ++e) {
        int s = col[e];
        uint2 v = *(const uint2*)(yd + (size_t)s * 512 + cb);
        a0 += bflo(v.x); a1 += bfhi(v.x); a2 += bflo(v.y); a3 += bfhi(v.y);
    }
    inv = 1.f / (float)max(t1 - t0, 1);
    uint2 lv = *(const uint2*)(ys + (size_t)d * 768 + 512 + cb);
    float h0 = fmaxf(m0 + a0 * inv + bflo(lv.x) + bias[cb + 0], 0.f);
    float h1 = fmaxf(m1 + a1 * inv + bfhi(lv.x) + bias[cb + 1], 0.f);
    float h2 = fmaxf(m2 + a2 * inv + bflo(lv.y) + bias[cb + 2], 0.f);
    float h3 = fmaxf(m3 + a3 * inv + bfhi(lv.y) + bias[cb + 3], 0.f);
    uint2 o;
    o.x = (unsigned)f2bf(h0) | ((unsigned)f2bf(h1) << 16);
    o.y = (unsigned)f2bf(h2) | ((unsigned)f2bf(h3) << 16);
    *(uint2*)(hout + (size_t)d * 256 + cb) = o;
}

__global__ __launch_bounds__(256) void fused_doc_l1(
    const ushort* __restrict__ ys, const ushort* __restrict__ yd,
    const int* __restrict__ rowptr, const int* __restrict__ col,
    const float* __restrict__ bias, ushort* __restrict__ hout, int NS, int ND) {
    int d = blockIdx.x * 4 + (threadIdx.x >> 6);
    if (d >= ND) return;
    int lane = threadIdx.x & 63;
    int cb = lane * 4;
    float a0 = 0, a1 = 0, a2 = 0, a3 = 0;
    int s0 = rowptr[2 * NS + d], s1 = rowptr[2 * NS + d + 1];
    for (int e = s0; e < s1; ++e) {
        int s = col[e];
        uint2 v = *(const uint2*)(ys + (size_t)s * 768 + cb);
        a0 += bflo(v.x); a1 += bfhi(v.x); a2 += bflo(v.y); a3 += bfhi(v.y);
    }
    float inv = 1.f / (float)max(s1 - s0, 1);
    uint2 lv = *(const uint2*)(yd + (size_t)d * 512 + 256 + cb);
    float h0 = fmaxf(a0 * inv + bflo(lv.x) + bias[cb + 0], 0.f);
    float h1 = fmaxf(a1 * inv + bfhi(lv.x) + bias[cb + 1], 0.f);
    float h2 = fmaxf(a2 * inv + bflo(lv.y) + bias[cb + 2], 0.f);
    float h3 = fmaxf(a3 * inv + bfhi(lv.y) + bias[cb + 3], 0.f);
    uint2 o;
    o.x = (unsigned)f2bf(h0) | ((unsigned)f2bf(h1) << 16);
    o.y = (unsigned)f2bf(h2) | ((unsigned)f2bf(h3) << 16);
    *(uint2*)(hout + (size_t)d * 256 + cb) = o;
}

__global__ __launch_bounds__(256) void fused_sent_l2(
    const ushort* __restrict__ ys, const ushort* __restrict__ yd,
    const int* __restrict__ rowptr, const int* __restrict__ col,
    const float* __restrict__ bias, const float* __restrict__ w,
    const int* __restrict__ gid, float* __restrict__ out, int NS, int G) {
    __shared__ float part[4][32];
    const int tid = threadIdx.x;
    const int lane = tid & 63, wv = tid >> 6;
    const int cb = lane * 2;
    float racc = 0.f;
    const int nw = gridDim.x * 4;
    for (int d = blockIdx.x * 4 + wv; d < NS; d += nw) {
        float a0 = 0.f, a1 = 0.f;
        int s0 = rowptr[d], s1 = rowptr[d + 1];
        for (int e = s0; e < s1; ++e) {
            int s = col[e];
            unsigned v = *(const unsigned*)(ys + (size_t)s * 384 + 128 + cb);
            a0 += bflo(v); a1 += bfhi(v);
        }
        float inv = 1.f / (float)max(s1 - s0, 1);
        float m0 = a0 * inv, m1 = a1 * inv;
        a0 = 0.f; a1 = 0.f;
        int t0 = rowptr[NS + d], t1 = rowptr[NS + d + 1];
        for (int e = t0; e < t1; ++e) {
            int s = col[e];
            unsigned v = *(const unsigned*)(yd + (size_t)s * 256 + cb);
            a0 += bflo(v); a1 += bfhi(v);
        }
        inv = 1.f / (float)max(t1 - t0, 1);
        unsigned lv = *(const unsigned*)(ys + (size_t)d * 384 + 256 + cb);
        float h0 = fmaxf(m0 + a0 * inv + bflo(lv) + bias[cb + 0], 0.f);
        float h1 = fmaxf(m1 + a1 * inv + bfhi(lv) + bias[cb + 1], 0.f);
        float sc = h0 * w[cb] + h1 * w[cb + 1];
#pragma unroll
        for (int o = 32; o; o >>= 1) sc += __shfl_down(sc, o);
        sc = __shfl(sc, 0);
        if (lane == gid[d]) racc += sc;
    }
    if (lane < 32) part[wv][lane] = racc;
    __syncthreads();
    if (tid < G) atomicAdd(&out[tid], part[0][tid] + part[1][tid] + part[2][tid] + part[3][tid]);
}

__global__ __launch_bounds__(256) void fused_doc_l2(
    const ushort* __restrict__ ys, const ushort* __restrict__ yd,
    const int* __restrict__ rowptr, const int* __restrict__ col,
    const float* __restrict__ bias, const float* __restrict__ w,
    const int* __restrict__ gid, float* __restrict__ out, int NS, int ND, int G) {
    __shared__ float part[4][32];
    const int tid = threadIdx.x;
    const int lane = tid & 63, wv = tid >> 6;
    const int cb = lane * 2;
    float racc = 0.f;
    const int nw = gridDim.x * 4;
    for (int d = blockIdx.x * 4 + wv; d < ND; d += nw) {
        float a0 = 0.f, a1 = 0.f;
        int s0 = rowptr[2 * NS + d], s1 = rowptr[2 * NS + d + 1];
        for (int e = s0; e < s1; ++e) {
            int s = col[e];
            unsigned v = *(const unsigned*)(ys + (size_t)s * 384 + cb);
            a0 += bflo(v); a1 += bfhi(v);
        }
        float inv = 1.f / (float)max(s1 - s0, 1);
        unsigned lv = *(const unsigned*)(yd + (size_t)d * 256 + 128 + cb);
        float h0 = fmaxf(a0 * inv + bflo(lv) + bias[cb + 0], 0.f);
        float h1 = fmaxf(a1 * inv + bfhi(lv) + bias[cb + 1], 0.f);
        float sc = h0 * w[cb] + h1 * w[cb + 1];
#pragma unroll
        for (int o = 32; o; o >>= 1) sc += __shfl_down(sc, o);
        sc = __shfl(sc, 0);
        if (lane == gid[d]) racc += sc;
    }
    if (lane < 32) part[wv][lane] = racc;
    __syncthreads();
    if (tid < G) atomicAdd(&out[tid], part[0][tid] + part[1][tid] + part[2][tid] + part[3][tid]);
}

__global__ void init_out(float* __restrict__ out, const float* __restrict__ b, int G) {
    int i = threadIdx.x;
    if (i < G) out[i] = b[0];
}

// ---------------- launch ----------------

extern "C" void kernel_launch(void* const* d_in, const int* in_sizes, int n_in,
                              void* d_out, int out_size, void* d_ws, size_t ws_size,
                              hipStream_t stream) {
    const float* x_sent = (const float*)d_in[0];
    const float* x_doc  = (const float*)d_in[1];
    const float* coeff1 = (const float*)d_in[2];
    const float* basis1 = (const float*)d_in[3];
    const float* loopw1 = (const float*)d_in[4];
    const float* bias1  = (const float*)d_in[5];
    const float* coeff2 = (const float*)d_in[6];
    const float* basis2 = (const float*)d_in[7];
    const float* loopw2 = (const float*)d_in[8];
    const float* bias2  = (const float*)d_in[9];
    const float* wscore = (const float*)d_in[10];
    const float* bscore = (const float*)d_in[11];
    const int* src_ss = (const int*)d_in[12];
    const int* dst_ss = (const int*)d_in[13];
    const int* src_sd = (const int*)d_in[14];
    const int* dst_sd = (const int*)d_in[15];
    const int* src_ds = (const int*)d_in[16];
    const int* dst_ds = (const int*)d_in[17];
    const int* gid_sent = (const int*)d_in[18];
    const int* gid_doc  = (const int*)d_in[19];

    const int DIN = 768, DH = 256, DOo = 128;
    const int NS = in_sizes[0] / DIN;     // 100000
    const int ND = in_sizes[1] / DIN;     // 10000
    const int E_SS = in_sizes[12], E_SD = in_sizes[14], E_DS = in_sizes[16];
    const int NTOT = NS + NS + ND;        // deg slots: [0,NS)=ss, [NS,2NS)=ds, [2NS,+ND)=sd
    const int ETOT = E_SS + E_DS + E_SD;
    const int G = out_size;               // 32
    float* out = (float*)d_out;

    char* base = (char*)d_ws;
    size_t off = 0;
    auto alloc = [&](size_t bytes) -> char* {
        char* p = base + off;
        off = (off + bytes + 255) & ~(size_t)255;
        return p;
    };
    ushort* B1sT = (ushort*)alloc((size_t)768 * 768 * 2);
    ushort* B1dT = (ushort*)alloc((size_t)512 * 768 * 2);
    ushort* B2sT = (ushort*)alloc((size_t)384 * 256 * 2);
    ushort* B2dT = (ushort*)alloc((size_t)256 * 256 * 2);
    ushort* xs_bf = (ushort*)alloc((size_t)NS * 768 * 2);
    ushort* xd_bf = (ushort*)alloc((size_t)ND * 768 * 2);
    ushort* ys1 = (ushort*)alloc((size_t)NS * 768 * 2);
    ushort* yd1 = (ushort*)alloc((size_t)ND * 512 * 2);
    ushort* h1s = (ushort*)alloc((size_t)NS * 256 * 2);
    ushort* h1d = (ushort*)alloc((size_t)ND * 256 * 2);
    int* deg  = (int*)alloc((size_t)2 * NTOT * 4);
    int* fill = deg + NTOT;
    int* rowptr = (int*)alloc((size_t)(NTOT + 1) * 4);
    int* bsum = (int*)alloc(256 * 4);
    int* colall = (int*)alloc((size_t)ETOT * 4);
    ushort* ys2 = xs_bf;                        // [NS][384], aliases dead xs_bf
    ushort* yd2 = xs_bf + (size_t)NS * 384;     // [ND][256]

    // ---- weights (transposed bf16) ----
    long long t1 = (long long)768 * DH, t2 = (long long)256 * DOo;
    long long KN1 = t1, KN2 = t2;
    int bt1 = (int)CDIV(t1, 256), bt2 = (int)CDIV(t2, 256);
    fill_basis_T<<<bt1, 256, 0, stream>>>(B1sT, 768, 0,       basis1, KN1, coeff1, 0, DH, t1);
    fill_basis_T<<<bt1, 256, 0, stream>>>(B1sT, 768, DH,      basis1, KN1, coeff1, 2, DH, t1);
    fill_copy_T <<<bt1, 256, 0, stream>>>(B1sT, 768, 2 * DH,  loopw1, DH, t1);
    fill_basis_T<<<bt1, 256, 0, stream>>>(B1dT, 768, 0,       basis1, KN1, coeff1, 1, DH, t1);
    fill_copy_T <<<bt1, 256, 0, stream>>>(B1dT, 768, DH,      loopw1, DH, t1);
    fill_basis_T<<<bt2, 256, 0, stream>>>(B2sT, 256, 0,        basis2, KN2, coeff2, 0, DOo, t2);
    fill_basis_T<<<bt2, 256, 0, stream>>>(B2sT, 256, DOo,      basis2, KN2, coeff2, 2, DOo, t2);
    fill_copy_T <<<bt2, 256, 0, stream>>>(B2sT, 256, 2 * DOo,  loopw2, DOo, t2);
    fill_basis_T<<<bt2, 256, 0, stream>>>(B2dT, 256, 0,        basis2, KN2, coeff2, 1, DOo, t2);
    fill_copy_T <<<bt2, 256, 0, stream>>>(B2dT, 256, DOo,      loopw2, DOo, t2);

    // ---- convert inputs to bf16 ----
    cvt_bf16_k<<<(int)CDIV((long long)NS * 768 / 8, 256), 256, 0, stream>>>(
        (const float4*)x_sent, (uint4*)xs_bf, (long long)NS * 768 / 8);
    cvt_bf16_k<<<(int)CDIV((long long)ND * 768 / 8, 256), 256, 0, stream>>>(
        (const float4*)x_doc, (uint4*)xd_bf, (long long)ND * 768 / 8);

    // ---- CSR build (joint over all 3 relations) ----
    zero_f4<<<(int)CDIV(2 * NTOT / 4, 256), 256, 0, stream>>>((float4*)deg, 2 * NTOT / 4);
    accum_deg_i<<<CDIV(E_SS, 256), 256, 0, stream>>>(dst_ss, E_SS, 0,      deg);
    accum_deg_i<<<CDIV(E_DS, 256), 256, 0, stream>>>(dst_ds, E_DS, NS,     deg);
    accum_deg_i<<<CDIV(E_SD, 256), 256, 0, stream>>>(dst_sd, E_SD, 2 * NS, deg);
    int nb = CDIV(NTOT, 1024);
    scan_p1<<<nb, 256, 0, stream>>>(deg, NTOT, bsum);
    scan_p2<<<1, 256, 0, stream>>>(bsum, nb, rowptr, NTOT, ETOT);
    scan_p3<<<nb, 256, 0, stream>>>(deg, NTOT, bsum, rowptr);
    fill_csr<<<CDIV(E_SS, 256), 256, 0, stream>>>(src_ss, dst_ss, E_SS, 0,      rowptr, fill, colall);
    fill_csr<<<CDIV(E_DS, 256), 256, 0, stream>>>(src_ds, dst_ds, E_DS, NS,     rowptr, fill, colall);
    fill_csr<<<CDIV(E_SD, 256), 256, 0, stream>>>(src_sd, dst_sd, E_SD, 2 * NS, rowptr, fill, colall);

    // ---- layer 1 ----
    {
        dim3 g(768 / 128, CDIV(NS, 128));
        gemm_bf16<<<g, 256, 0, stream>>>(xs_bf, B1sT, ys1, NS, 768, 768);
    }
    {
        dim3 g(512 / 128, CDIV(ND, 128));
        gemm_bf16<<<g, 256, 0, stream>>>(xd_bf, B1dT, yd1, ND, 768, 512);
    }
    fused_sent_l1<<<CDIV(NS, 4), 256, 0, stream>>>(ys1, yd1, rowptr, colall, bias1, h1s, NS);
    fused_doc_l1 <<<CDIV(ND, 4), 256, 0, stream>>>(ys1, yd1, rowptr, colall, bias1, h1d, NS, ND);

    // ---- layer 2 ----
    {
        dim3 g(384 / 128, CDIV(NS, 128));
        gemm_bf16<<<g, 256, 0, stream>>>(h1s, B2sT, ys2, NS, 256, 384);
    }
    {
        dim3 g(256 / 128, CDIV(ND, 128));
        gemm_bf16<<<g, 256, 0, stream>>>(h1d, B2dT, yd2, ND, 256, 256);
    }
    init_out<<<1, 64, 0, stream>>>(out, bscore, G);
    fused_sent_l2<<<1024, 256, 0, stream>>>(ys2, yd2, rowptr, colall, bias2, wscore, gid_sent, out, NS, G);
    fused_doc_l2 <<<256, 256, 0, stream>>>(ys2, yd2, rowptr, colall, bias2, wscore, gid_doc, out, NS, ND, G);
}

// Round 5
// 1051.194 us; speedup vs baseline: 6.9720x; 1.1117x over previous
//
#include <hip/hip_runtime.h>

#define CDIV(a,b) (((a)+(b)-1)/(b))

typedef __attribute__((ext_vector_type(8))) short bf16x8;
typedef __attribute__((ext_vector_type(4))) float floatx4;

__device__ __forceinline__ ushort f2bf(float x) {
    unsigned u = __float_as_uint(x);
    return (ushort)((u + 0x7fffu + ((u >> 16) & 1u)) >> 16);   // RNE
}
__device__ __forceinline__ float bflo(unsigned v) { return __uint_as_float(v << 16); }
__device__ __forceinline__ float bfhi(unsigned v) { return __uint_as_float(v & 0xffff0000u); }

__device__ __forceinline__ void load_lds16(const ushort* g, ushort* l) {
    __builtin_amdgcn_global_load_lds(
        (const __attribute__((address_space(1))) void*)g,
        (__attribute__((address_space(3))) void*)l, 16, 0, 0);
}

// ---------------- utility kernels ----------------

__global__ void zero_f4(float4* __restrict__ p, long long n4) {
    long long i = blockIdx.x * 256LL + threadIdx.x;
    if (i < n4) p[i] = make_float4(0.f, 0.f, 0.f, 0.f);
}

// fused f32->bf16 conversion for both node sets
__global__ void cvt_all(const float4* __restrict__ xs, const float4* __restrict__ xd,
                        uint4* __restrict__ os, uint4* __restrict__ od,
                        long long n8s, long long n8d) {
    long long i = blockIdx.x * 256LL + threadIdx.x;
    const float4* in; uint4* out; long long j;
    if (i < n8s) { in = xs; out = os; j = i; }
    else if (i < n8s + n8d) { in = xd; out = od; j = i - n8s; }
    else return;
    float4 a = in[2 * j], b = in[2 * j + 1];
    uint4 o;
    o.x = (unsigned)f2bf(a.x) | ((unsigned)f2bf(a.y) << 16);
    o.y = (unsigned)f2bf(a.z) | ((unsigned)f2bf(a.w) << 16);
    o.z = (unsigned)f2bf(b.x) | ((unsigned)f2bf(b.y) << 16);
    o.w = (unsigned)f2bf(b.z) | ((unsigned)f2bf(b.w) << 16);
    out[j] = o;
}

// One layer's 5 weight blocks, transposed bf16. sections (blockIdx.y):
// 0: BsT col0=0   rel0 | 1: BsT col0=N rel2 | 2: BsT col0=2N loop | 3: BdT col0=0 rel1 | 4: BdT col0=N loop
__global__ void fill_w5(ushort* __restrict__ BsT, ushort* __restrict__ BdT,
                        const float* __restrict__ basis, const float* __restrict__ loopw,
                        const float* __restrict__ coeff, int K, int N, long long KN) {
    long long i = blockIdx.x * 256LL + threadIdx.x;
    if (i >= KN) return;
    int k = (int)(i % K), n = (int)(i / K);
    int sec = blockIdx.y;
    float val;
    if (sec == 2 || sec == 4) {
        val = loopw[(size_t)k * N + n];
    } else {
        int r = (sec == 0) ? 0 : (sec == 1) ? 2 : 1;
        val = coeff[2 * r] * basis[(size_t)k * N + n] + coeff[2 * r + 1] * basis[KN + (size_t)k * N + n];
    }
    ushort* dst = (sec < 3) ? BsT : BdT;
    int col0 = (sec == 0) ? 0 : (sec == 1) ? N : (sec == 2) ? 2 * N : (sec == 3) ? 0 : N;
    dst[(size_t)(col0 + n) * K + k] = f2bf(val);
}

// ---------------- CSR build ----------------

__global__ void accum_deg_all(const int* __restrict__ dss, const int* __restrict__ dds,
                              const int* __restrict__ dsd, int nss, int nds, int nsd,
                              int NS, int* __restrict__ deg) {
    int i = blockIdx.x * 256 + threadIdx.x;
    if (i < nss) atomicAdd(&deg[dss[i]], 1);
    else if (i < nss + nds) atomicAdd(&deg[NS + dds[i - nss]], 1);
    else if (i < nss + nds + nsd) atomicAdd(&deg[2 * NS + dsd[i - nss - nds]], 1);
}

__global__ void scan_p1(const int* __restrict__ deg, int n, int* __restrict__ bsum) {
    __shared__ int sd[256];
    int blk = blockIdx.x, tid = threadIdx.x;
    int i0 = blk * 1024 + tid * 4;
    int s = 0;
#pragma unroll
    for (int j = 0; j < 4; ++j) if (i0 + j < n) s += deg[i0 + j];
    sd[tid] = s; __syncthreads();
    for (int o = 128; o; o >>= 1) {
        if (tid < o) sd[tid] += sd[tid + o];
        __syncthreads();
    }
    if (tid == 0) bsum[blk] = sd[0];
}

__global__ void scan_p2(int* __restrict__ bsum, int nb, int* __restrict__ rowptr, int ntot, int etot) {
    __shared__ int sd[256];
    int tid = threadIdx.x;
    int v = (tid < nb) ? bsum[tid] : 0;
    sd[tid] = v; __syncthreads();
    for (int o = 1; o < 256; o <<= 1) {
        int t = (tid >= o) ? sd[tid - o] : 0;
        __syncthreads();
        sd[tid] += t;
        __syncthreads();
    }
    if (tid < nb) bsum[tid] = sd[tid] - v;
    if (tid == 0) rowptr[ntot] = etot;
}

__global__ void scan_p3(const int* __restrict__ deg, int n, const int* __restrict__ bsum,
                        int* __restrict__ rowptr) {
    __shared__ int sd[256];
    int blk = blockIdx.x, tid = threadIdx.x;
    int i0 = blk * 1024 + tid * 4;
    int v[4]; int s = 0;
#pragma unroll
    for (int j = 0; j < 4; ++j) { v[j] = (i0 + j < n) ? deg[i0 + j] : 0; s += v[j]; }
    sd[tid] = s; __syncthreads();
    for (int o = 1; o < 256; o <<= 1) {
        int t = (tid >= o) ? sd[tid - o] : 0;
        __syncthreads();
        sd[tid] += t;
        __syncthreads();
    }
    int excl = bsum[blk] + sd[tid] - s;
#pragma unroll
    for (int j = 0; j < 4; ++j) {
        if (i0 + j < n) rowptr[i0 + j] = excl;
        excl += v[j];
    }
}

__global__ void fill_csr_all(const int* __restrict__ sss, const int* __restrict__ dss,
                             const int* __restrict__ sds, const int* __restrict__ dds,
                             const int* __restrict__ ssd, const int* __restrict__ dsd,
                             int nss, int nds, int nsd, int NS,
                             const int* __restrict__ rowptr, int* __restrict__ fill,
                             int* __restrict__ col) {
    int i = blockIdx.x * 256 + threadIdx.x;
    int d, s;
    if (i < nss) { d = dss[i]; s = sss[i]; }
    else if (i < nss + nds) { int j = i - nss; d = NS + dds[j]; s = sds[j]; }
    else if (i < nss + nds + nsd) { int j = i - nss - nds; d = 2 * NS + dsd[j]; s = ssd[j]; }
    else return;
    int p = rowptr[d] + atomicAdd(&fill[d], 1);
    col[p] = s;
}

// ---------------- MFMA GEMM: C[M,N] bf16 = A[M,K] bf16 @ Bt[N,K]^T ----------------
__global__ __launch_bounds__(256) void gemm_bf16(
    const ushort* __restrict__ A, const ushort* __restrict__ Bt, ushort* __restrict__ C,
    int M, int K, int N) {
    __shared__ ushort As[128 * 32];
    __shared__ ushort Bs[128 * 32];
    const int tid = threadIdx.x;
    const int bn = blockIdx.x * 128;
    const long long bm = blockIdx.y * 128LL;
    const int lane = tid & 63, wave = tid >> 6;
    const int mo = (wave & 1) * 64, no = (wave >> 1) * 64;
    const int l15 = lane & 15, quad = lane >> 4;
    const int srow0 = wave * 16 + (lane >> 2);
    const int schunk = (lane & 3) * 8;
    floatx4 acc[4][4] = {};

    for (int k0 = 0; k0 < K; k0 += 32) {
#pragma unroll
        for (int t = 0; t < 2; ++t) {
            int row = t * 64 + srow0;
            long long ar = bm + row; if (ar >= M) ar = M - 1;
            load_lds16(A + ar * (size_t)K + k0 + schunk, As + t * 2048 + wave * 512);
            load_lds16(Bt + (size_t)(bn + row) * K + k0 + schunk, Bs + t * 2048 + wave * 512);
        }
        __syncthreads();
        bf16x8 af[4], bfr[4];
#pragma unroll
        for (int mt = 0; mt < 4; ++mt)
            af[mt] = *(const bf16x8*)(As + (mo + mt * 16 + l15) * 32 + quad * 8);
#pragma unroll
        for (int nt = 0; nt < 4; ++nt)
            bfr[nt] = *(const bf16x8*)(Bs + (no + nt * 16 + l15) * 32 + quad * 8);
#pragma unroll
        for (int mt = 0; mt < 4; ++mt)
#pragma unroll
            for (int nt = 0; nt < 4; ++nt)
                acc[mt][nt] = __builtin_amdgcn_mfma_f32_16x16x32_bf16(af[mt], bfr[nt], acc[mt][nt], 0, 0, 0);
        __syncthreads();
    }
#pragma unroll
    for (int mt = 0; mt < 4; ++mt)
#pragma unroll
        for (int i = 0; i < 4; ++i) {
            long long row = bm + mo + mt * 16 + quad * 4 + i;
            if (row < M) {
#pragma unroll
                for (int nt = 0; nt < 4; ++nt)
                    C[row * (size_t)N + bn + no + nt * 16 + l15] = f2bf(acc[mt][nt][i]);
            }
        }
}

// ---------------- fused gather kernels (sent + doc merged) ----------------
// one wave per dst node; edge loops unrolled x4 for memory-level parallelism

__global__ __launch_bounds__(256) void gather_l1(
    const ushort* __restrict__ ys, const ushort* __restrict__ yd,
    const int* __restrict__ rowptr, const int* __restrict__ col,
    const float* __restrict__ bias, ushort* __restrict__ h1s, ushort* __restrict__ h1d,
    int NS, int ND) {
    int d = blockIdx.x * 4 + (threadIdx.x >> 6);
    int lane = threadIdx.x & 63;
    int cb = lane * 4;
    float b0 = bias[cb], b1 = bias[cb + 1], b2 = bias[cb + 2], b3 = bias[cb + 3];
    if (d < NS) {
        // ---- sent dst: mean_ss(ys[:,256:512]) + mean_ds(yd[:,0:256]) + ys[d,512:768] ----
        float a0 = 0, a1 = 0, a2 = 0, a3 = 0;
        int s0 = rowptr[d], s1 = rowptr[d + 1];
        int e = s0;
        for (; e + 4 <= s1; e += 4) {
            int sA = col[e], sB = col[e + 1], sC = col[e + 2], sD = col[e + 3];
            uint2 vA = *(const uint2*)(ys + (size_t)sA * 768 + 256 + cb);
            uint2 vB = *(const uint2*)(ys + (size_t)sB * 768 + 256 + cb);
            uint2 vC = *(const uint2*)(ys + (size_t)sC * 768 + 256 + cb);
            uint2 vD = *(const uint2*)(ys + (size_t)sD * 768 + 256 + cb);
            a0 += bflo(vA.x) + bflo(vB.x) + bflo(vC.x) + bflo(vD.x);
            a1 += bfhi(vA.x) + bfhi(vB.x) + bfhi(vC.x) + bfhi(vD.x);
            a2 += bflo(vA.y) + bflo(vB.y) + bflo(vC.y) + bflo(vD.y);
            a3 += bfhi(vA.y) + bfhi(vB.y) + bfhi(vC.y) + bfhi(vD.y);
        }
        for (; e < s1; ++e) {
            int s = col[e];
            uint2 v = *(const uint2*)(ys + (size_t)s * 768 + 256 + cb);
            a0 += bflo(v.x); a1 += bfhi(v.x); a2 += bflo(v.y); a3 += bfhi(v.y);
        }
        float inv = 1.f / (float)max(s1 - s0, 1);
        float m0 = a0 * inv, m1 = a1 * inv, m2 = a2 * inv, m3 = a3 * inv;
        a0 = a1 = a2 = a3 = 0.f;
        int t0 = rowptr[NS + d], t1 = rowptr[NS + d + 1];
        for (e = t0; e < t1; ++e) {
            int s = col[e];
            uint2 v = *(const uint2*)(yd + (size_t)s * 512 + cb);
            a0 += bflo(v.x); a1 += bfhi(v.x); a2 += bflo(v.y); a3 += bfhi(v.y);
        }
        inv = 1.f / (float)max(t1 - t0, 1);
        uint2 lv = *(const uint2*)(ys + (size_t)d * 768 + 512 + cb);
        float h0 = fmaxf(m0 + a0 * inv + bflo(lv.x) + b0, 0.f);
        float h1 = fmaxf(m1 + a1 * inv + bfhi(lv.x) + b1, 0.f);
        float h2 = fmaxf(m2 + a2 * inv + bflo(lv.y) + b2, 0.f);
        float h3 = fmaxf(m3 + a3 * inv + bfhi(lv.y) + b3, 0.f);
        uint2 o;
        o.x = (unsigned)f2bf(h0) | ((unsigned)f2bf(h1) << 16);
        o.y = (unsigned)f2bf(h2) | ((unsigned)f2bf(h3) << 16);
        *(uint2*)(h1s + (size_t)d * 256 + cb) = o;
    } else if (d < NS + ND) {
        // ---- doc dst: mean_sd(ys[:,0:256]) + yd[dd,256:512] ----
        int dd = d - NS;
        float a0 = 0, a1 = 0, a2 = 0, a3 = 0;
        int s0 = rowptr[2 * NS + dd], s1 = rowptr[2 * NS + dd + 1];
        int e = s0;
        for (; e + 4 <= s1; e += 4) {
            int sA = col[e], sB = col[e + 1], sC = col[e + 2], sD = col[e + 3];
            uint2 vA = *(const uint2*)(ys + (size_t)sA * 768 + cb);
            uint2 vB = *(const uint2*)(ys + (size_t)sB * 768 + cb);
            uint2 vC = *(const uint2*)(ys + (size_t)sC * 768 + cb);
            uint2 vD = *(const uint2*)(ys + (size_t)sD * 768 + cb);
            a0 += bflo(vA.x) + bflo(vB.x) + bflo(vC.x) + bflo(vD.x);
            a1 += bfhi(vA.x) + bfhi(vB.x) + bfhi(vC.x) + bfhi(vD.x);
            a2 += bflo(vA.y) + bflo(vB.y) + bflo(vC.y) + bflo(vD.y);
            a3 += bfhi(vA.y) + bfhi(vB.y) + bfhi(vC.y) + bfhi(vD.y);
        }
        for (; e < s1; ++e) {
            int s = col[e];
            uint2 v = *(const uint2*)(ys + (size_t)s * 768 + cb);
            a0 += bflo(v.x); a1 += bfhi(v.x); a2 += bflo(v.y); a3 += bfhi(v.y);
        }
        float inv = 1.f / (float)max(s1 - s0, 1);
        uint2 lv = *(const uint2*)(yd + (size_t)dd * 512 + 256 + cb);
        float h0 = fmaxf(a0 * inv + bflo(lv.x) + b0, 0.f);
        float h1 = fmaxf(a1 * inv + bfhi(lv.x) + b1, 0.f);
        float h2 = fmaxf(a2 * inv + bflo(lv.y) + b2, 0.f);
        float h3 = fmaxf(a3 * inv + bfhi(lv.y) + b3, 0.f);
        uint2 o;
        o.x = (unsigned)f2bf(h0) | ((unsigned)f2bf(h1) << 16);
        o.y = (unsigned)f2bf(h2) | ((unsigned)f2bf(h3) << 16);
        *(uint2*)(h1d + (size_t)dd * 256 + cb) = o;
    }
}

__global__ __launch_bounds__(256) void gather_l2(
    const ushort* __restrict__ ys, const ushort* __restrict__ yd,
    const int* __restrict__ rowptr, const int* __restrict__ col,
    const float* __restrict__ bias, const float* __restrict__ w,
    const int* __restrict__ gid_s, const int* __restrict__ gid_d,
    float* __restrict__ out, int NS, int ND, int G) {
    __shared__ float part[4][32];
    const int tid = threadIdx.x;
    const int lane = tid & 63, wv = tid >> 6;
    const int cb = lane * 2;
    const float w0 = w[cb], w1 = w[cb + 1];
    const float b0 = bias[cb], b1 = bias[cb + 1];
    float racc = 0.f;
    const int nw = gridDim.x * 4;
    for (int d = blockIdx.x * 4 + wv; d < NS + ND; d += nw) {
        float h0, h1; int g;
        if (d < NS) {
            float a0 = 0.f, a1 = 0.f;
            int s0 = rowptr[d], s1 = rowptr[d + 1];
            int e = s0;
            for (; e + 4 <= s1; e += 4) {
                int sA = col[e], sB = col[e + 1], sC = col[e + 2], sD = col[e + 3];
                unsigned vA = *(const unsigned*)(ys + (size_t)sA * 384 + 128 + cb);
                unsigned vB = *(const unsigned*)(ys + (size_t)sB * 384 + 128 + cb);
                unsigned vC = *(const unsigned*)(ys + (size_t)sC * 384 + 128 + cb);
                unsigned vD = *(const unsigned*)(ys + (size_t)sD * 384 + 128 + cb);
                a0 += bflo(vA) + bflo(vB) + bflo(vC) + bflo(vD);
                a1 += bfhi(vA) + bfhi(vB) + bfhi(vC) + bfhi(vD);
            }
            for (; e < s1; ++e) {
                int s = col[e];
                unsigned v = *(const unsigned*)(ys + (size_t)s * 384 + 128 + cb);
                a0 += bflo(v); a1 += bfhi(v);
            }
            float inv = 1.f / (float)max(s1 - s0, 1);
            float m0 = a0 * inv, m1 = a1 * inv;
            a0 = 0.f; a1 = 0.f;
            int t0 = rowptr[NS + d], t1 = rowptr[NS + d + 1];
            for (e = t0; e < t1; ++e) {
                int s = col[e];
                unsigned v = *(const unsigned*)(yd + (size_t)s * 256 + cb);
                a0 += bflo(v); a1 += bfhi(v);
            }
            inv = 1.f / (float)max(t1 - t0, 1);
            unsigned lv = *(const unsigned*)(ys + (size_t)d * 384 + 256 + cb);
            h0 = fmaxf(m0 + a0 * inv + bflo(lv) + b0, 0.f);
            h1 = fmaxf(m1 + a1 * inv + bfhi(lv) + b1, 0.f);
            g = gid_s[d];
        } else {
            int dd = d - NS;
            float a0 = 0.f, a1 = 0.f;
            int s0 = rowptr[2 * NS + dd], s1 = rowptr[2 * NS + dd + 1];
            int e = s0;
            for (; e + 4 <= s1; e += 4) {
                int sA = col[e], sB = col[e + 1], sC = col[e + 2], sD = col[e + 3];
                unsigned vA = *(const unsigned*)(ys + (size_t)sA * 384 + cb);
                unsigned vB = *(const unsigned*)(ys + (size_t)sB * 384 + cb);
                unsigned vC = *(const unsigned*)(ys + (size_t)sC * 384 + cb);
                unsigned vD = *(const unsigned*)(ys + (size_t)sD * 384 + cb);
                a0 += bflo(vA) + bflo(vB) + bflo(vC) + bflo(vD);
                a1 += bfhi(vA) + bfhi(vB) + bfhi(vC) + bfhi(vD);
            }
            for (; e < s1; ++e) {
                int s = col[e];
                unsigned v = *(const unsigned*)(ys + (size_t)s * 384 + cb);
                a0 += bflo(v); a1 += bfhi(v);
            }
            float inv = 1.f / (float)max(s1 - s0, 1);
            unsigned lv = *(const unsigned*)(yd + (size_t)dd * 256 + 128 + cb);
            h0 = fmaxf(a0 * inv + bflo(lv) + b0, 0.f);
            h1 = fmaxf(a1 * inv + bfhi(lv) + b1, 0.f);
            g = gid_d[dd];
        }
        float sc = h0 * w0 + h1 * w1;
#pragma unroll
        for (int o = 32; o; o >>= 1) sc += __shfl_down(sc, o);
        sc = __shfl(sc, 0);
        if (lane == g) racc += sc;
    }
    if (lane < 32) part[wv][lane] = racc;
    __syncthreads();
    if (tid < G) atomicAdd(&out[tid], part[0][tid] + part[1][tid] + part[2][tid] + part[3][tid]);
}

__global__ void init_out(float* __restrict__ out, const float* __restrict__ b, int G) {
    int i = threadIdx.x;
    if (i < G) out[i] = b[0];
}

// ---------------- launch ----------------

extern "C" void kernel_launch(void* const* d_in, const int* in_sizes, int n_in,
                              void* d_out, int out_size, void* d_ws, size_t ws_size,
                              hipStream_t stream) {
    const float* x_sent = (const float*)d_in[0];
    const float* x_doc  = (const float*)d_in[1];
    const float* coeff1 = (const float*)d_in[2];
    const float* basis1 = (const float*)d_in[3];
    const float* loopw1 = (const float*)d_in[4];
    const float* bias1  = (const float*)d_in[5];
    const float* coeff2 = (const float*)d_in[6];
    const float* basis2 = (const float*)d_in[7];
    const float* loopw2 = (const float*)d_in[8];
    const float* bias2  = (const float*)d_in[9];
    const float* wscore = (const float*)d_in[10];
    const float* bscore = (const float*)d_in[11];
    const int* src_ss = (const int*)d_in[12];
    const int* dst_ss = (const int*)d_in[13];
    const int* src_sd = (const int*)d_in[14];
    const int* dst_sd = (const int*)d_in[15];
    const int* src_ds = (const int*)d_in[16];
    const int* dst_ds = (const int*)d_in[17];
    const int* gid_sent = (const int*)d_in[18];
    const int* gid_doc  = (const int*)d_in[19];

    const int DIN = 768, DH = 256, DOo = 128;
    const int NS = in_sizes[0] / DIN;     // 100000
    const int ND = in_sizes[1] / DIN;     // 10000
    const int E_SS = in_sizes[12], E_SD = in_sizes[14], E_DS = in_sizes[16];
    const int NTOT = NS + NS + ND;
    const int ETOT = E_SS + E_DS + E_SD;
    const int G = out_size;
    float* out = (float*)d_out;

    char* base = (char*)d_ws;
    size_t off = 0;
    auto alloc = [&](size_t bytes) -> char* {
        char* p = base + off;
        off = (off + bytes + 255) & ~(size_t)255;
        return p;
    };
    ushort* B1sT = (ushort*)alloc((size_t)768 * 768 * 2);
    ushort* B1dT = (ushort*)alloc((size_t)512 * 768 * 2);
    ushort* B2sT = (ushort*)alloc((size_t)384 * 256 * 2);
    ushort* B2dT = (ushort*)alloc((size_t)256 * 256 * 2);
    ushort* xs_bf = (ushort*)alloc((size_t)NS * 768 * 2);
    ushort* xd_bf = (ushort*)alloc((size_t)ND * 768 * 2);
    ushort* ys1 = (ushort*)alloc((size_t)NS * 768 * 2);
    ushort* yd1 = (ushort*)alloc((size_t)ND * 512 * 2);
    ushort* h1s = (ushort*)alloc((size_t)NS * 256 * 2);
    ushort* h1d = (ushort*)alloc((size_t)ND * 256 * 2);
    int* deg  = (int*)alloc((size_t)2 * NTOT * 4);
    int* fill = deg + NTOT;
    int* rowptr = (int*)alloc((size_t)(NTOT + 1) * 4);
    int* bsum = (int*)alloc(256 * 4);
    int* colall = (int*)alloc((size_t)ETOT * 4);
    ushort* ys2 = xs_bf;                        // [NS][384], aliases dead xs_bf
    ushort* yd2 = xs_bf + (size_t)NS * 384;     // [ND][256]

    // ---- weights (1 kernel per layer, 5 sections each) ----
    long long t1 = (long long)768 * DH, t2 = (long long)256 * DOo;
    fill_w5<<<dim3((unsigned)CDIV(t1, 256), 5), 256, 0, stream>>>(B1sT, B1dT, basis1, loopw1, coeff1, 768, DH, t1);
    fill_w5<<<dim3((unsigned)CDIV(t2, 256), 5), 256, 0, stream>>>(B2sT, B2dT, basis2, loopw2, coeff2, 256, DOo, t2);

    // ---- inputs to bf16 (1 kernel) ----
    long long n8s = (long long)NS * 96, n8d = (long long)ND * 96;
    cvt_all<<<(int)CDIV(n8s + n8d, 256), 256, 0, stream>>>(
        (const float4*)x_sent, (const float4*)x_doc, (uint4*)xs_bf, (uint4*)xd_bf, n8s, n8d);

    // ---- CSR build ----
    zero_f4<<<(int)CDIV(2 * NTOT / 4, 256), 256, 0, stream>>>((float4*)deg, 2 * NTOT / 4);
    accum_deg_all<<<CDIV(ETOT, 256), 256, 0, stream>>>(dst_ss, dst_ds, dst_sd, E_SS, E_DS, E_SD, NS, deg);
    int nb = CDIV(NTOT, 1024);
    scan_p1<<<nb, 256, 0, stream>>>(deg, NTOT, bsum);
    scan_p2<<<1, 256, 0, stream>>>(bsum, nb, rowptr, NTOT, ETOT);
    scan_p3<<<nb, 256, 0, stream>>>(deg, NTOT, bsum, rowptr);
    fill_csr_all<<<CDIV(ETOT, 256), 256, 0, stream>>>(src_ss, dst_ss, src_ds, dst_ds, src_sd, dst_sd,
                                                      E_SS, E_DS, E_SD, NS, rowptr, fill, colall);

    // ---- layer 1 GEMMs (sent split into two M-halves for profiler visibility) ----
    {
        int mb = CDIV(NS, 128), mb0 = mb / 2;
        int M0 = mb0 * 128;
        gemm_bf16<<<dim3(6, mb0), 256, 0, stream>>>(xs_bf, B1sT, ys1, M0, 768, 768);
        gemm_bf16<<<dim3(6, mb - mb0), 256, 0, stream>>>(
            xs_bf + (size_t)M0 * 768, B1sT, ys1 + (size_t)M0 * 768, NS - M0, 768, 768);
    }
    gemm_bf16<<<dim3(4, CDIV(ND, 128)), 256, 0, stream>>>(xd_bf, B1dT, yd1, ND, 768, 512);

    gather_l1<<<CDIV(NS + ND, 4), 256, 0, stream>>>(ys1, yd1, rowptr, colall, bias1, h1s, h1d, NS, ND);

    // ---- layer 2 ----
    gemm_bf16<<<dim3(3, CDIV(NS, 128)), 256, 0, stream>>>(h1s, B2sT, ys2, NS, 256, 384);
    gemm_bf16<<<dim3(2, CDIV(ND, 128)), 256, 0, stream>>>(h1d, B2dT, yd2, ND, 256, 256);

    init_out<<<1, 64, 0, stream>>>(out, bscore, G);
    gather_l2<<<1100, 256, 0, stream>>>(ys2, yd2, rowptr, colall, bias2, wscore,
                                        gid_sent, gid_doc, out, NS, ND, G);
}